// Round 1
// baseline (3730.185 us; speedup 1.0000x reference)
//
#include <hip/hip_runtime.h>
#include <math.h>

// ---------------------------------------------------------------------------
// Generic tiled fp32 GEMM: C = alpha * A @ B(^T) + bias, optional ReLU.
// A: [M,K] row-major. B: [K,N] row-major (TRANS_B=false) or [N,K] (TRANS_B=true).
// Batched via blockIdx.z with element strides sA/sB/sC.
// Tile 64x64, BK=16, 256 threads, 4x4 micro-tile per thread.
// ---------------------------------------------------------------------------
template<bool TRANS_B, bool RELU>
__global__ __launch_bounds__(256)
void gemm_f32(const float* __restrict__ A, const float* __restrict__ B,
              const float* __restrict__ bias, float* __restrict__ C,
              int M, int N, int K,
              long long sA, long long sB, long long sC, float alpha)
{
    constexpr int BM = 64, BN = 64, BK = 16;
    A += (long long)blockIdx.z * sA;
    B += (long long)blockIdx.z * sB;
    C += (long long)blockIdx.z * sC;

    __shared__ float As[BK][BM];
    __shared__ float Bs[BK][BN];

    const int tid = threadIdx.x;
    const int tx  = tid & 15;       // 0..15  -> 4 cols each
    const int ty  = tid >> 4;       // 0..15  -> 4 rows each
    const int row0 = blockIdx.y * BM;
    const int col0 = blockIdx.x * BN;

    float acc[4][4] = {};

    for (int k0 = 0; k0 < K; k0 += BK) {
        // load A tile: As[k][m] = A[row0+m][k0+k]
        #pragma unroll
        for (int i = 0; i < 4; ++i) {
            int idx = tid + i * 256;
            int kk = idx & (BK - 1);
            int m  = idx >> 4;
            int gr = row0 + m, gk = k0 + kk;
            As[kk][m] = (gr < M && gk < K) ? A[(long long)gr * K + gk] : 0.f;
        }
        // load B tile: Bs[k][n]
        #pragma unroll
        for (int i = 0; i < 4; ++i) {
            int idx = tid + i * 256;
            if (!TRANS_B) {
                int n  = idx & (BN - 1);
                int kk = idx >> 6;
                int gk = k0 + kk, gn = col0 + n;
                Bs[kk][n] = (gk < K && gn < N) ? B[(long long)gk * N + gn] : 0.f;
            } else {
                int kk = idx & (BK - 1);
                int n  = idx >> 4;
                int gk = k0 + kk, gn = col0 + n;
                Bs[kk][n] = (gk < K && gn < N) ? B[(long long)gn * K + gk] : 0.f;
            }
        }
        __syncthreads();

        #pragma unroll
        for (int kk = 0; kk < BK; ++kk) {
            float4 a4 = *reinterpret_cast<const float4*>(&As[kk][ty * 4]);
            float4 b4 = *reinterpret_cast<const float4*>(&Bs[kk][tx * 4]);
            float av[4] = {a4.x, a4.y, a4.z, a4.w};
            float bv[4] = {b4.x, b4.y, b4.z, b4.w};
            #pragma unroll
            for (int i = 0; i < 4; ++i)
                #pragma unroll
                for (int j = 0; j < 4; ++j)
                    acc[i][j] = fmaf(av[i], bv[j], acc[i][j]);
        }
        __syncthreads();
    }

    #pragma unroll
    for (int i = 0; i < 4; ++i) {
        int gr = row0 + ty * 4 + i;
        if (gr >= M) continue;
        #pragma unroll
        for (int j = 0; j < 4; ++j) {
            int gn = col0 + tx * 4 + j;
            if (gn >= N) continue;
            float v = acc[i][j] * alpha;
            if (bias) v += bias[gn];
            if (RELU) v = fmaxf(v, 0.f);
            C[(long long)gr * N + gn] = v;
        }
    }
}

// ---------------------------------------------------------------------------
// Ktot[b,d] = sum_s k[b,s,d]   (one thread per (b,d))
// ---------------------------------------------------------------------------
__global__ void ktot_kernel(const float* __restrict__ k, float* __restrict__ ktot,
                            int B, int S, int D)
{
    int idx = blockIdx.x * blockDim.x + threadIdx.x;
    if (idx >= B * D) return;
    int b = idx / D, d = idx % D;
    const float* kp = k + (long long)b * S * D + d;
    float s = 0.f;
    for (int t = 0; t < S; ++t) s += kp[(long long)t * D];
    ktot[idx] = s;
}

// ---------------------------------------------------------------------------
// kk[b,s,d] = (Ktot[b,d] + (e-1)*window_sum) / Z_s  — analytic softmax(mask)@k
// ---------------------------------------------------------------------------
__global__ void kk_kernel(const float* __restrict__ k, const float* __restrict__ ktot,
                          float* __restrict__ kk, int B, int S, int D)
{
    long long idx = (long long)blockIdx.x * blockDim.x + threadIdx.x;
    long long n = (long long)B * S * D;
    if (idx >= n) return;
    int d = (int)(idx % D);
    long long bs = idx / D;
    int s = (int)(bs % S);
    int b = (int)(bs / S);
    int lo = s - 2 > 0 ? s - 2 : 0;
    int hi = s + 2 < S - 1 ? s + 2 : S - 1;
    int c = hi - lo + 1;
    const float E = 2.718281828459045f;
    float w = 0.f;
    const float* kp = k + ((long long)b * S + lo) * D + d;
    for (int t = lo; t <= hi; ++t, kp += D) w += *kp;
    float Z = (float)(S - c) + E * (float)c;
    kk[idx] = (ktot[b * D + d] + (E - 1.f) * w) / Z;
}

// ---------------------------------------------------------------------------
// Row softmax in place. One block per row of length S.
// ---------------------------------------------------------------------------
__global__ void softmax_rows(float* __restrict__ sc, int S)
{
    long long row = blockIdx.x;
    float* p = sc + row * (long long)S;
    int tid = threadIdx.x;
    __shared__ float red[256];

    float m = -INFINITY;
    for (int t = tid; t < S; t += 256) m = fmaxf(m, p[t]);
    red[tid] = m; __syncthreads();
    for (int s = 128; s > 0; s >>= 1) {
        if (tid < s) red[tid] = fmaxf(red[tid], red[tid + s]);
        __syncthreads();
    }
    m = red[0];
    __syncthreads();

    float sum = 0.f;
    for (int t = tid; t < S; t += 256) {
        float e = __expf(p[t] - m);
        p[t] = e;
        sum += e;
    }
    red[tid] = sum; __syncthreads();
    for (int s = 128; s > 0; s >>= 1) {
        if (tid < s) red[tid] += red[tid + s];
        __syncthreads();
    }
    float inv = 1.f / red[0];
    for (int t = tid; t < S; t += 256) p[t] *= inv;
}

// ---------------------------------------------------------------------------
// z = a + f, plus per-block fp64 partial sums of z and z^2 (deterministic).
// ---------------------------------------------------------------------------
__global__ void add_reduce(const float* __restrict__ a, const float* __restrict__ f,
                           float* __restrict__ z, double* __restrict__ part, long long n)
{
    __shared__ double rs[256], rs2[256];
    int tid = threadIdx.x;
    long long i = (long long)blockIdx.x * blockDim.x + tid;
    long long stride = (long long)gridDim.x * blockDim.x;
    double s = 0.0, s2 = 0.0;
    for (; i < n; i += stride) {
        float zi = a[i] + f[i];
        z[i] = zi;
        s  += (double)zi;
        s2 += (double)zi * (double)zi;
    }
    rs[tid] = s; rs2[tid] = s2; __syncthreads();
    for (int k = 128; k > 0; k >>= 1) {
        if (tid < k) { rs[tid] += rs[tid + k]; rs2[tid] += rs2[tid + k]; }
        __syncthreads();
    }
    if (tid == 0) {
        part[2 * blockIdx.x]     = rs[0];
        part[2 * blockIdx.x + 1] = rs2[0];
    }
}

__global__ void finish_stats(const double* __restrict__ part, int npart,
                             float* __restrict__ stats, double n)
{
    __shared__ double rs[256], rs2[256];
    int tid = threadIdx.x;
    double s = 0.0, s2 = 0.0;
    for (int i = tid; i < npart; i += 256) { s += part[2 * i]; s2 += part[2 * i + 1]; }
    rs[tid] = s; rs2[tid] = s2; __syncthreads();
    for (int k = 128; k > 0; k >>= 1) {
        if (tid < k) { rs[tid] += rs[tid + k]; rs2[tid] += rs2[tid + k]; }
        __syncthreads();
    }
    if (tid == 0) {
        double mu  = rs[0] / n;
        double var = rs2[0] / n - mu * mu;
        stats[0] = (float)mu;
        stats[1] = (float)(1.0 / sqrt(var + 1e-6));
    }
}

__global__ void norm_apply(const float* __restrict__ z, const float* __restrict__ nw,
                           const float* __restrict__ nb, const float* __restrict__ stats,
                           float* __restrict__ out, long long n)
{
    float mu = stats[0], rstd = stats[1];
    long long i = (long long)blockIdx.x * blockDim.x + threadIdx.x;
    long long stride = (long long)gridDim.x * blockDim.x;
    for (; i < n; i += stride)
        out[i] = (z[i] - mu) * rstd * nw[i] + nb[i];
}

// ---------------------------------------------------------------------------
// Host-side orchestration
// ---------------------------------------------------------------------------
static void gemm_launch(bool transB, bool relu,
                        const float* A, const float* B, const float* bias, float* C,
                        int M, int N, int K, int batch,
                        long long sA, long long sB, long long sC,
                        float alpha, hipStream_t st)
{
    dim3 grid((N + 63) / 64, (M + 63) / 64, batch);
    if (transB)
        gemm_f32<true , false><<<grid, 256, 0, st>>>(A, B, bias, C, M, N, K, sA, sB, sC, alpha);
    else if (relu)
        gemm_f32<false, true ><<<grid, 256, 0, st>>>(A, B, bias, C, M, N, K, sA, sB, sC, alpha);
    else
        gemm_f32<false, false><<<grid, 256, 0, st>>>(A, B, bias, C, M, N, K, sA, sB, sC, alpha);
}

static void run_branch(const float* x,
                       const float* Wq, const float* bq, const float* Wk, const float* bk,
                       const float* Wv, const float* bv, const float* W1, const float* b1,
                       const float* W2, const float* b2, const float* nw, const float* nb,
                       float* out, int B, int S, int D, char* ws, hipStream_t st)
{
    // Workspace offsets sized by the text branch (the larger one):
    const long long MDmax = 4096LL * 1024;   // B*S*D   (text)
    const long long Hmax  = 4096LL * 4096;   // B*S*4D  (text)
    float*  q    = (float*)ws;
    float*  kb   = q    + MDmax;
    float*  vb   = kb   + MDmax;
    float*  kkb  = vb   + MDmax;
    float*  sc   = kkb  + MDmax;            // scores; FFN hidden overlaps this
    float*  h    = sc;
    double* part = (double*)(sc + Hmax);    // 2048 doubles
    float*  stats= (float*)(part + 2048);   // 2 floats
    float*  ktot = stats + 2;               // B*D floats

    long long M = (long long)B * S;
    long long n = M * D;
    float inv_sqrt_d = (float)(1.0 / sqrt((double)D));

    // q,k,v projections
    gemm_launch(false, false, x, Wq, bq, q,  (int)M, D, D, 1, 0, 0, 0, 1.f, st);
    gemm_launch(false, false, x, Wk, bk, kb, (int)M, D, D, 1, 0, 0, 0, 1.f, st);
    gemm_launch(false, false, x, Wv, bv, vb, (int)M, D, D, 1, 0, 0, 0, 1.f, st);

    // kk = softmax(band_mask) @ k   (analytic: total + (e-1)*window sums)
    int bd = B * D;
    ktot_kernel<<<(bd + 255) / 256, 256, 0, st>>>(kb, ktot, B, S, D);
    kk_kernel<<<(int)((n + 255) / 256), 256, 0, st>>>(kb, ktot, kkb, B, S, D);

    // scores = q @ kk^T / sqrt(D)   (batched over B)
    gemm_launch(true, false, q, kkb, nullptr, sc, S, S, D, B,
                (long long)S * D, (long long)S * D, (long long)S * S, inv_sqrt_d, st);
    softmax_rows<<<B * S, 256, 0, st>>>(sc, S);
    // attn_out = P @ v  -> reuse q buffer
    gemm_launch(false, false, sc, vb, nullptr, q, S, D, S, B,
                (long long)S * S, (long long)S * D, (long long)S * D, 1.f, st);

    // norm1: y1 = whole_norm(attn_out + x)
    add_reduce<<<1024, 256, 0, st>>>(q, x, vb, part, n);     // z -> vb
    finish_stats<<<1, 256, 0, st>>>(part, 1024, stats, (double)n);
    norm_apply<<<2048, 256, 0, st>>>(vb, nw, nb, stats, kb, n);  // y1 -> kb

    // FFN
    gemm_launch(false, true , kb, W1, b1, h,   (int)M, 4 * D, D, 1, 0, 0, 0, 1.f, st);
    gemm_launch(false, false, h,  W2, b2, kkb, (int)M, D, 4 * D, 1, 0, 0, 0, 1.f, st);

    // norm2: out = whole_norm(ffn_out + x)
    add_reduce<<<1024, 256, 0, st>>>(kkb, x, vb, part, n);
    finish_stats<<<1, 256, 0, st>>>(part, 1024, stats, (double)n);
    norm_apply<<<2048, 256, 0, st>>>(vb, nw, nb, stats, out, n);
}

extern "C" void kernel_launch(void* const* d_in, const int* in_sizes, int n_in,
                              void* d_out, int out_size, void* d_ws, size_t ws_size,
                              hipStream_t stream)
{
    const float* text  = (const float*)d_in[0];
    const float* image = (const float*)d_in[1];
    const float* t[12];
    const float* im[12];
    for (int i = 0; i < 12; ++i) t[i]  = (const float*)d_in[2 + i];
    for (int i = 0; i < 12; ++i) im[i] = (const float*)d_in[14 + i];

    float* out_text = (float*)d_out;                 // [8,512,1024]
    float* out_img  = out_text + 8LL * 512 * 1024;   // [8,196,768]
    char* ws = (char*)d_ws;

    // text branch: B=8, S=512, D=1024
    run_branch(text, t[0], t[1], t[2], t[3], t[4], t[5], t[6], t[7], t[8], t[9], t[10], t[11],
               out_text, 8, 512, 1024, ws, stream);
    // image branch: B=8, S=196, D=768 (reuses the same workspace)
    run_branch(image, im[0], im[1], im[2], im[3], im[4], im[5], im[6], im[7], im[8], im[9], im[10], im[11],
               out_img, 8, 196, 768, ws, stream);
}

// Round 2
// 909.038 us; speedup vs baseline: 4.1034x; 4.1034x over previous
//
#include <hip/hip_runtime.h>
#include <math.h>

typedef float  f32x4  __attribute__((ext_vector_type(4)));
typedef short  bf16x8 __attribute__((ext_vector_type(8)));

__device__ __forceinline__ unsigned short f2bf(float f) {
    union { float f; unsigned u; } v; v.f = f;
    unsigned u = v.u;
    return (unsigned short)((u + 0x7FFFu + ((u >> 16) & 1u)) >> 16);
}

#define GLOAD_LDS16(g, l)                                                      \
    __builtin_amdgcn_global_load_lds(                                          \
        (const __attribute__((address_space(1))) void*)(g),                    \
        (__attribute__((address_space(3))) void*)(l), 16, 0, 0)

// ---------------------------------------------------------------------------
// bf16 MFMA GEMM, m97 structure: 128x128 tile, BK=32, 4 waves, global_load_lds.
// A: bf16 [M,K] lda; BT: bf16 [N,K] ldb (i.e. B transposed); C: fp32 or bf16.
// Batched via blockIdx.z (element strides sA/sB/sC).
// Requires: K % 32 == 0, lda/ldb % 8 == 0, staging rows may over-read up to
// 127 rows past M/N bound (buffers are allocated with slack).
// ---------------------------------------------------------------------------
template<bool OUT_BF16, bool RELU>
__global__ __launch_bounds__(256)
void gemm_bf16(const unsigned short* __restrict__ A,
               const unsigned short* __restrict__ BT,
               const float* __restrict__ bias, void* __restrict__ Cv,
               int M, int N, int K, int lda, int ldb, int ldc,
               long long sA, long long sB, long long sC, float alpha)
{
    constexpr int BM = 128, BN = 128, BK = 32;
    __shared__ unsigned short Asm[BM * BK];
    __shared__ unsigned short Bsm[BN * BK];

    A  += (long long)blockIdx.z * sA;
    BT += (long long)blockIdx.z * sB;
    char* Cb = (char*)Cv + (long long)blockIdx.z * sC * (OUT_BF16 ? 2 : 4);

    const int tid  = threadIdx.x;
    const int lane = tid & 63;
    const int wave = tid >> 6;         // 0..3
    const int wr   = wave >> 1;        // 0..1
    const int wc   = wave & 1;         // 0..1
    const int row0 = blockIdx.y * BM;
    const int col0 = blockIdx.x * BN;

    // staging: LDS byte p = issue*4096 + tid*16  ->  row = p>>6, kelem = (p&63)>>1
    const int srow = tid >> 2;         // 0..63
    const int skel = (tid & 3) * 8;

    f32x4 acc[4][4] = {};

    const int lrow = lane & 15;
    const int lk   = (lane >> 4) * 8;

    for (int k0 = 0; k0 < K; k0 += BK) {
        #pragma unroll
        for (int is = 0; is < 2; ++is) {
            const unsigned short* g =
                A + (long long)(row0 + is * 64 + srow) * lda + (k0 + skel);
            GLOAD_LDS16(g, &Asm[(is * 64 + srow) * BK + skel]);
        }
        #pragma unroll
        for (int is = 0; is < 2; ++is) {
            const unsigned short* g =
                BT + (long long)(col0 + is * 64 + srow) * ldb + (k0 + skel);
            GLOAD_LDS16(g, &Bsm[(is * 64 + srow) * BK + skel]);
        }
        __syncthreads();   // compiler emits vmcnt(0)+lgkmcnt(0) drain before barrier

        bf16x8 af[4], bf[4];
        #pragma unroll
        for (int mf = 0; mf < 4; ++mf)
            af[mf] = *(const bf16x8*)&Asm[(wr * 64 + mf * 16 + lrow) * BK + lk];
        #pragma unroll
        for (int nf = 0; nf < 4; ++nf)
            bf[nf] = *(const bf16x8*)&Bsm[(wc * 64 + nf * 16 + lrow) * BK + lk];
        #pragma unroll
        for (int mf = 0; mf < 4; ++mf)
            #pragma unroll
            for (int nf = 0; nf < 4; ++nf)
                acc[mf][nf] = __builtin_amdgcn_mfma_f32_16x16x32_bf16(
                    af[mf], bf[nf], acc[mf][nf], 0, 0, 0);
        __syncthreads();
    }

    // C/D layout: col = lane&15, row = (lane>>4)*4 + j   [m89 verified]
    const int crow = (lane >> 4) * 4;
    const int ccol = lane & 15;
    #pragma unroll
    for (int mf = 0; mf < 4; ++mf) {
        int rbase = row0 + wr * 64 + mf * 16 + crow;
        #pragma unroll
        for (int nf = 0; nf < 4; ++nf) {
            int c = col0 + wc * 64 + nf * 16 + ccol;
            if (c >= N) continue;
            float bv = bias ? bias[c] : 0.f;
            #pragma unroll
            for (int j = 0; j < 4; ++j) {
                int r = rbase + j;
                if (r >= M) continue;
                float v = acc[mf][nf][j] * alpha + bv;
                if (RELU) v = fmaxf(v, 0.f);
                if (OUT_BF16)
                    ((unsigned short*)Cb)[(long long)r * ldc + c] = f2bf(v);
                else
                    ((float*)Cb)[(long long)r * ldc + c] = v;
            }
        }
    }
}

// ---------------------------------------------------------------------------
// elementwise cast f32 -> bf16 (vectorized 4-wide)
// ---------------------------------------------------------------------------
__global__ void cast_bf16_kernel(const float4* __restrict__ in,
                                 ushort4* __restrict__ out, long long n4)
{
    long long i = (long long)blockIdx.x * blockDim.x + threadIdx.x;
    long long stride = (long long)gridDim.x * blockDim.x;
    for (; i < n4; i += stride) {
        float4 v = in[i];
        ushort4 o;
        o.x = f2bf(v.x); o.y = f2bf(v.y); o.z = f2bf(v.z); o.w = f2bf(v.w);
        out[i] = o;
    }
}

// ---------------------------------------------------------------------------
// transpose + cast: src f32 [R,C] -> dst bf16 [C, Rpad], rows R..Rpad-1 = 0.
// grid: (ceil(Rpad/32), ceil(C/32), batch), block 256 (32x8)
// ---------------------------------------------------------------------------
__global__ void transpose_cast_kernel(const float* __restrict__ src,
                                      unsigned short* __restrict__ dst,
                                      int R, int C, int Rpad,
                                      long long sSrc, long long sDst)
{
    __shared__ float t[32][33];
    src += (long long)blockIdx.z * sSrc;
    dst += (long long)blockIdx.z * sDst;
    int r0 = blockIdx.x * 32, c0 = blockIdx.y * 32;
    int tx = threadIdx.x & 31, ty = threadIdx.x >> 5;
    #pragma unroll
    for (int i = 0; i < 32; i += 8) {
        int r = r0 + ty + i, c = c0 + tx;
        t[ty + i][tx] = (r < R && c < C) ? src[(long long)r * C + c] : 0.f;
    }
    __syncthreads();
    #pragma unroll
    for (int i = 0; i < 32; i += 8) {
        int c = c0 + ty + i, r = r0 + tx;
        if (c < C && r < Rpad)
            dst[(long long)c * Rpad + r] = f2bf(t[tx][ty + i]);
    }
}

// ---------------------------------------------------------------------------
// Ktot[b,d] = sum_s k[b,s,d]
// ---------------------------------------------------------------------------
__global__ void ktot_kernel(const float* __restrict__ k, float* __restrict__ ktot,
                            int B, int S, int D)
{
    int idx = blockIdx.x * blockDim.x + threadIdx.x;
    if (idx >= B * D) return;
    int b = idx / D, d = idx % D;
    const float* kp = k + (long long)b * S * D + d;
    float s = 0.f;
    for (int t = 0; t < S; ++t) s += kp[(long long)t * D];
    ktot[idx] = s;
}

// ---------------------------------------------------------------------------
// kk[b,s,d] = (Ktot[b,d] + (e-1)*window_sum) / Z_s  -> bf16 (4-wide over d)
// ---------------------------------------------------------------------------
__global__ void kk_kernel(const float* __restrict__ k, const float* __restrict__ ktot,
                          unsigned short* __restrict__ kk, int B, int S, int D)
{
    long long idx = (long long)blockIdx.x * blockDim.x + threadIdx.x;
    int D4 = D >> 2;
    long long n4 = (long long)B * S * D4;
    if (idx >= n4) return;
    int d4 = (int)(idx % D4);
    long long bs = idx / D4;
    int s = (int)(bs % S);
    int b = (int)(bs / S);
    int lo = s - 2 > 0 ? s - 2 : 0;
    int hi = s + 2 < S - 1 ? s + 2 : S - 1;
    int c = hi - lo + 1;
    const float E = 2.718281828459045f;
    float Zinv = 1.f / ((float)(S - c) + E * (float)c);

    const float4* kp = (const float4*)(k + ((long long)b * S + lo) * D) + d4;
    float4 w = {0.f, 0.f, 0.f, 0.f};
    for (int t = lo; t <= hi; ++t, kp += D4) {
        float4 kv = *kp;
        w.x += kv.x; w.y += kv.y; w.z += kv.z; w.w += kv.w;
    }
    float4 tot = *((const float4*)(ktot + b * D) + d4);
    ushort4 o;
    o.x = f2bf((tot.x + (E - 1.f) * w.x) * Zinv);
    o.y = f2bf((tot.y + (E - 1.f) * w.y) * Zinv);
    o.z = f2bf((tot.z + (E - 1.f) * w.z) * Zinv);
    o.w = f2bf((tot.w + (E - 1.f) * w.w) * Zinv);
    ((ushort4*)(kk + ((long long)b * S + s) * D))[d4] = o;
}

// ---------------------------------------------------------------------------
// row softmax: fp32 scores [rows][Spad] (valid cols < S) -> bf16 P, pads = 0
// ---------------------------------------------------------------------------
__global__ void softmax_rows_bf16(const float* __restrict__ sc,
                                  unsigned short* __restrict__ P, int S, int Spad)
{
    long long row = blockIdx.x;
    const float* p = sc + row * (long long)Spad;
    unsigned short* o = P + row * (long long)Spad;
    int tid = threadIdx.x;
    __shared__ float red[256];

    float m = -INFINITY;
    for (int t = tid; t < S; t += 256) m = fmaxf(m, p[t]);
    red[tid] = m; __syncthreads();
    for (int s = 128; s > 0; s >>= 1) {
        if (tid < s) red[tid] = fmaxf(red[tid], red[tid + s]);
        __syncthreads();
    }
    m = red[0];
    __syncthreads();

    float sum = 0.f;
    for (int t = tid; t < S; t += 256) sum += __expf(p[t] - m);
    red[tid] = sum; __syncthreads();
    for (int s = 128; s > 0; s >>= 1) {
        if (tid < s) red[tid] += red[tid + s];
        __syncthreads();
    }
    float inv = 1.f / red[0];
    for (int t = tid; t < Spad; t += 256)
        o[t] = (t < S) ? f2bf(__expf(p[t] - m) * inv) : (unsigned short)0;
}

// ---------------------------------------------------------------------------
// whole-norm stats over z = a + f (fp64 partials, fixed deterministic tree)
// ---------------------------------------------------------------------------
__global__ void stats_kernel(const float4* __restrict__ a, const float4* __restrict__ f,
                             double* __restrict__ part, long long n4)
{
    __shared__ double rs[256], rs2[256];
    int tid = threadIdx.x;
    long long i = (long long)blockIdx.x * blockDim.x + tid;
    long long stride = (long long)gridDim.x * blockDim.x;
    double s = 0.0, s2 = 0.0;
    for (; i < n4; i += stride) {
        float4 av = a[i], fv = f[i];
        float z0 = av.x + fv.x, z1 = av.y + fv.y, z2 = av.z + fv.z, z3 = av.w + fv.w;
        s  += (double)z0 + (double)z1 + (double)z2 + (double)z3;
        s2 += (double)z0 * z0 + (double)z1 * z1 + (double)z2 * z2 + (double)z3 * z3;
    }
    rs[tid] = s; rs2[tid] = s2; __syncthreads();
    for (int k = 128; k > 0; k >>= 1) {
        if (tid < k) { rs[tid] += rs[tid + k]; rs2[tid] += rs2[tid + k]; }
        __syncthreads();
    }
    if (tid == 0) { part[2 * blockIdx.x] = rs[0]; part[2 * blockIdx.x + 1] = rs2[0]; }
}

__global__ void finish_stats(const double* __restrict__ part, int npart,
                             float* __restrict__ stats, double n)
{
    __shared__ double rs[256], rs2[256];
    int tid = threadIdx.x;
    double s = 0.0, s2 = 0.0;
    for (int i = tid; i < npart; i += 256) { s += part[2 * i]; s2 += part[2 * i + 1]; }
    rs[tid] = s; rs2[tid] = s2; __syncthreads();
    for (int k = 128; k > 0; k >>= 1) {
        if (tid < k) { rs[tid] += rs[tid + k]; rs2[tid] += rs2[tid + k]; }
        __syncthreads();
    }
    if (tid == 0) {
        double mu  = rs[0] / n;
        double var = rs2[0] / n - mu * mu;
        stats[0] = (float)mu;
        stats[1] = (float)(1.0 / sqrt(var + 1e-6));
    }
}

// norm apply, recomputing z = a + f on the fly; OUT_BF16 selects output type
template<bool OUT_BF16>
__global__ void norm_apply_kernel(const float4* __restrict__ a, const float4* __restrict__ f,
                                  const float4* __restrict__ nw, const float4* __restrict__ nb,
                                  const float* __restrict__ stats, void* __restrict__ out,
                                  long long n4)
{
    float mu = stats[0], rstd = stats[1];
    long long i = (long long)blockIdx.x * blockDim.x + threadIdx.x;
    long long stride = (long long)gridDim.x * blockDim.x;
    for (; i < n4; i += stride) {
        float4 av = a[i], fv = f[i], wv = nw[i], bv = nb[i];
        float o0 = (av.x + fv.x - mu) * rstd * wv.x + bv.x;
        float o1 = (av.y + fv.y - mu) * rstd * wv.y + bv.y;
        float o2 = (av.z + fv.z - mu) * rstd * wv.z + bv.z;
        float o3 = (av.w + fv.w - mu) * rstd * wv.w + bv.w;
        if (OUT_BF16) {
            ushort4 o; o.x = f2bf(o0); o.y = f2bf(o1); o.z = f2bf(o2); o.w = f2bf(o3);
            ((ushort4*)out)[i] = o;
        } else {
            float4 o = {o0, o1, o2, o3};
            ((float4*)out)[i] = o;
        }
    }
}

// ---------------------------------------------------------------------------
// host-side orchestration
// ---------------------------------------------------------------------------
static void gemm(bool outBf16, bool relu,
                 const unsigned short* A, const unsigned short* BT, const float* bias,
                 void* C, int M, int N, int K, int lda, int ldb, int ldc,
                 int batch, long long sA, long long sB, long long sC,
                 float alpha, hipStream_t st)
{
    dim3 grid((N + 127) / 128, (M + 127) / 128, batch);
    if (outBf16) {
        if (relu) gemm_bf16<true , true ><<<grid, 256, 0, st>>>(A, BT, bias, C, M, N, K, lda, ldb, ldc, sA, sB, sC, alpha);
        else      gemm_bf16<true , false><<<grid, 256, 0, st>>>(A, BT, bias, C, M, N, K, lda, ldb, ldc, sA, sB, sC, alpha);
    } else {
        if (relu) gemm_bf16<false, true ><<<grid, 256, 0, st>>>(A, BT, bias, C, M, N, K, lda, ldb, ldc, sA, sB, sC, alpha);
        else      gemm_bf16<false, false><<<grid, 256, 0, st>>>(A, BT, bias, C, M, N, K, lda, ldb, ldc, sA, sB, sC, alpha);
    }
}

struct Bufs {
    unsigned short *xb, *qb, *kkb, *vT, *P, *y1b, *h, *WqT, *WkT, *WvT, *W1T, *W2T;
    float *f32buf, *scores, *ktot, *stats;
    double *part;
};

static void run_branch(const float* x, const float* const* w,  // 12 params
                       float* out, int B, int S, int D, const Bufs& wsb, hipStream_t st)
{
    const float *Wq = w[0], *bq = w[1], *Wk = w[2], *bk = w[3], *Wv = w[4], *bv = w[5];
    const float *W1 = w[6], *b1 = w[7], *W2 = w[8], *b2 = w[9], *nw = w[10], *nb = w[11];

    const int Spad = (S + 31) & ~31;
    const long long M = (long long)B * S;
    const long long n = M * D;
    const long long n4 = n / 4;
    const float inv_sqrt_d = (float)(1.0 / sqrt((double)D));
    const int D4 = 4 * D;

    // casts: x -> xb ; weights -> transposed bf16
    cast_bf16_kernel<<<1024, 256, 0, st>>>((const float4*)x, (ushort4*)wsb.xb, n4);
    transpose_cast_kernel<<<dim3((D + 31) / 32, (D + 31) / 32, 1), 256, 0, st>>>(Wq, wsb.WqT, D, D, D, 0, 0);
    transpose_cast_kernel<<<dim3((D + 31) / 32, (D + 31) / 32, 1), 256, 0, st>>>(Wk, wsb.WkT, D, D, D, 0, 0);
    transpose_cast_kernel<<<dim3((D + 31) / 32, (D + 31) / 32, 1), 256, 0, st>>>(Wv, wsb.WvT, D, D, D, 0, 0);
    transpose_cast_kernel<<<dim3((D + 31) / 32, (D4 + 31) / 32, 1), 256, 0, st>>>(W1, wsb.W1T, D, D4, D, 0, 0);
    transpose_cast_kernel<<<dim3((D4 + 31) / 32, (D + 31) / 32, 1), 256, 0, st>>>(W2, wsb.W2T, D4, D, D4, 0, 0);

    // q (bf16), k (fp32 -> f32buf)
    gemm(true , false, wsb.xb, wsb.WqT, bq, wsb.qb,    (int)M, D, D, D, D, D, 1, 0, 0, 0, 1.f, st);
    gemm(false, false, wsb.xb, wsb.WkT, bk, wsb.f32buf,(int)M, D, D, D, D, D, 1, 0, 0, 0, 1.f, st);

    // kk = softmax(band mask) @ k  (analytic)  -> bf16
    int bd = B * D;
    ktot_kernel<<<(bd + 255) / 256, 256, 0, st>>>(wsb.f32buf, wsb.ktot, B, S, D);
    kk_kernel<<<(int)((n4 + 255) / 256), 256, 0, st>>>(wsb.f32buf, wsb.ktot, wsb.kkb, B, S, D);

    // v (fp32, overwrite k in f32buf) -> vT bf16 [B][D][Spad]
    gemm(false, false, wsb.xb, wsb.WvT, bv, wsb.f32buf, (int)M, D, D, D, D, D, 1, 0, 0, 0, 1.f, st);
    transpose_cast_kernel<<<dim3((Spad + 31) / 32, (D + 31) / 32, B), 256, 0, st>>>(
        wsb.f32buf, wsb.vT, S, D, Spad, (long long)S * D, (long long)D * Spad);

    // scores = q @ kk^T / sqrt(D)   (batched, fp32, ldc = Spad)
    gemm(false, false, wsb.qb, wsb.kkb, nullptr, wsb.scores, S, S, D, D, D, Spad,
         B, (long long)S * D, (long long)S * D, (long long)S * Spad, inv_sqrt_d, st);
    softmax_rows_bf16<<<(int)M, 256, 0, st>>>(wsb.scores, wsb.P, S, Spad);

    // attn = P @ v  (A = P [S,Spad] bf16, BT = vT [D,Spad]) -> f32buf
    gemm(false, false, wsb.P, wsb.vT, nullptr, wsb.f32buf, S, D, Spad, Spad, Spad, D,
         B, (long long)S * Spad, (long long)D * Spad, (long long)S * D, 1.f, st);

    // norm1: y1 = whole_norm(attn + x) -> bf16
    stats_kernel<<<1024, 256, 0, st>>>((const float4*)wsb.f32buf, (const float4*)x, wsb.part, n4);
    finish_stats<<<1, 256, 0, st>>>(wsb.part, 1024, wsb.stats, (double)n);
    norm_apply_kernel<true><<<2048, 256, 0, st>>>((const float4*)wsb.f32buf, (const float4*)x,
        (const float4*)nw, (const float4*)nb, wsb.stats, wsb.y1b, n4);

    // FFN
    gemm(true , true , wsb.y1b, wsb.W1T, b1, wsb.h,      (int)M, D4, D, D, D, D4, 1, 0, 0, 0, 1.f, st);
    gemm(false, false, wsb.h,   wsb.W2T, b2, wsb.f32buf, (int)M, D, D4, D4, D4, D, 1, 0, 0, 0, 1.f, st);

    // norm2: out = whole_norm(ffn + x) -> fp32
    stats_kernel<<<1024, 256, 0, st>>>((const float4*)wsb.f32buf, (const float4*)x, wsb.part, n4);
    finish_stats<<<1, 256, 0, st>>>(wsb.part, 1024, wsb.stats, (double)n);
    norm_apply_kernel<false><<<2048, 256, 0, st>>>((const float4*)wsb.f32buf, (const float4*)x,
        (const float4*)nw, (const float4*)nb, wsb.stats, out, n4);
}

extern "C" void kernel_launch(void* const* d_in, const int* in_sizes, int n_in,
                              void* d_out, int out_size, void* d_ws, size_t ws_size,
                              hipStream_t stream)
{
    const float* text  = (const float*)d_in[0];
    const float* image = (const float*)d_in[1];
    const float* tw[12];
    const float* iw[12];
    for (int i = 0; i < 12; ++i) tw[i] = (const float*)d_in[2 + i];
    for (int i = 0; i < 12; ++i) iw[i] = (const float*)d_in[14 + i];

    float* out_text = (float*)d_out;                 // [8,512,1024]
    float* out_img  = out_text + 8LL * 512 * 1024;   // [8,196,768]

    // workspace layout sized by the text branch (B=8,S=512,D=1024,Spad=512)
    char* p = (char*)d_ws;
    auto alloc = [&](long long bytes) {
        char* r = p;
        p += (bytes + 255) & ~255LL;
        return r;
    };
    const long long MD  = 4096LL * 1024;   // B*S*D
    const long long BDS = 8LL * 1024 * 512; // B*D*Spad
    const long long SS  = 8LL * 512 * 512;  // B*S*Spad
    Bufs b;
    b.xb     = (unsigned short*)alloc(MD * 2);
    b.qb     = (unsigned short*)alloc(MD * 2);
    b.kkb    = (unsigned short*)alloc(MD * 2);
    b.vT     = (unsigned short*)alloc(BDS * 2);
    b.P      = (unsigned short*)alloc(SS * 2);
    b.y1b    = (unsigned short*)alloc(MD * 2);
    b.h      = (unsigned short*)alloc(MD * 4 * 2);
    b.WqT    = (unsigned short*)alloc(1024LL * 1024 * 2);
    b.WkT    = (unsigned short*)alloc(1024LL * 1024 * 2);
    b.WvT    = (unsigned short*)alloc(1024LL * 1024 * 2);
    b.W1T    = (unsigned short*)alloc(4096LL * 1024 * 2);
    b.W2T    = (unsigned short*)alloc(4096LL * 1024 * 2);
    b.f32buf = (float*)alloc(MD * 4);
    b.scores = (float*)alloc(SS * 4);
    b.ktot   = (float*)alloc(8192LL * 4);
    b.part   = (double*)alloc(2048LL * 8);
    b.stats  = (float*)alloc(256);

    run_branch(text,  tw, out_text, 8, 512, 1024, b, stream);
    run_branch(image, iw, out_img,  8, 196, 768,  b, stream);
}

// Round 3
// 761.190 us; speedup vs baseline: 4.9005x; 1.1942x over previous
//
#include <hip/hip_runtime.h>
#include <math.h>

typedef float  f32x4  __attribute__((ext_vector_type(4)));
typedef short  bf16x8 __attribute__((ext_vector_type(8)));

__device__ __forceinline__ unsigned short f2bf(float f) {
    union { float f; unsigned u; } v; v.f = f;
    unsigned u = v.u;
    return (unsigned short)((u + 0x7FFFu + ((u >> 16) & 1u)) >> 16);
}

#define GLOAD_LDS16(g, l)                                                      \
    __builtin_amdgcn_global_load_lds(                                          \
        (const __attribute__((address_space(1))) void*)(g),                    \
        (__attribute__((address_space(3))) void*)(l), 16, 0, 0)

// ---------------------------------------------------------------------------
// bf16 MFMA GEMM, m97 structure: 128x128 tile, BK=32, 4 waves, global_load_lds.
// A: bf16 [M,K] lda; BT: bf16 [N,K] ldb (i.e. B transposed); C: fp32 or bf16.
// Batched via blockIdx.z (element strides sA/sB/sC).
// ---------------------------------------------------------------------------
template<bool OUT_BF16, bool RELU>
__global__ __launch_bounds__(256)
void gemm_bf16(const unsigned short* __restrict__ A,
               const unsigned short* __restrict__ BT,
               const float* __restrict__ bias, void* __restrict__ Cv,
               int M, int N, int K, int lda, int ldb, int ldc,
               long long sA, long long sB, long long sC, float alpha)
{
    constexpr int BM = 128, BN = 128, BK = 32;
    __shared__ unsigned short Asm[BM * BK];
    __shared__ unsigned short Bsm[BN * BK];

    A  += (long long)blockIdx.z * sA;
    BT += (long long)blockIdx.z * sB;
    char* Cb = (char*)Cv + (long long)blockIdx.z * sC * (OUT_BF16 ? 2 : 4);

    const int tid  = threadIdx.x;
    const int lane = tid & 63;
    const int wave = tid >> 6;         // 0..3
    const int wr   = wave >> 1;        // 0..1
    const int wc   = wave & 1;         // 0..1
    const int row0 = blockIdx.y * BM;
    const int col0 = blockIdx.x * BN;

    const int srow = tid >> 2;         // 0..63
    const int skel = (tid & 3) * 8;

    f32x4 acc[4][4] = {};

    const int lrow = lane & 15;
    const int lk   = (lane >> 4) * 8;

    for (int k0 = 0; k0 < K; k0 += BK) {
        #pragma unroll
        for (int is = 0; is < 2; ++is) {
            const unsigned short* g =
                A + (long long)(row0 + is * 64 + srow) * lda + (k0 + skel);
            GLOAD_LDS16(g, &Asm[(is * 64 + srow) * BK + skel]);
        }
        #pragma unroll
        for (int is = 0; is < 2; ++is) {
            const unsigned short* g =
                BT + (long long)(col0 + is * 64 + srow) * ldb + (k0 + skel);
            GLOAD_LDS16(g, &Bsm[(is * 64 + srow) * BK + skel]);
        }
        __syncthreads();

        bf16x8 af[4], bf[4];
        #pragma unroll
        for (int mf = 0; mf < 4; ++mf)
            af[mf] = *(const bf16x8*)&Asm[(wr * 64 + mf * 16 + lrow) * BK + lk];
        #pragma unroll
        for (int nf = 0; nf < 4; ++nf)
            bf[nf] = *(const bf16x8*)&Bsm[(wc * 64 + nf * 16 + lrow) * BK + lk];
        #pragma unroll
        for (int mf = 0; mf < 4; ++mf)
            #pragma unroll
            for (int nf = 0; nf < 4; ++nf)
                acc[mf][nf] = __builtin_amdgcn_mfma_f32_16x16x32_bf16(
                    af[mf], bf[nf], acc[mf][nf], 0, 0, 0);
        __syncthreads();
    }

    const int crow = (lane >> 4) * 4;
    const int ccol = lane & 15;
    #pragma unroll
    for (int mf = 0; mf < 4; ++mf) {
        int rbase = row0 + wr * 64 + mf * 16 + crow;
        #pragma unroll
        for (int nf = 0; nf < 4; ++nf) {
            int c = col0 + wc * 64 + nf * 16 + ccol;
            if (c >= N) continue;
            float bv = bias ? bias[c] : 0.f;
            #pragma unroll
            for (int j = 0; j < 4; ++j) {
                int r = rbase + j;
                if (r >= M) continue;
                float v = acc[mf][nf][j] * alpha + bv;
                if (RELU) v = fmaxf(v, 0.f);
                if (OUT_BF16)
                    ((unsigned short*)Cb)[(long long)r * ldc + c] = f2bf(v);
                else
                    ((float*)Cb)[(long long)r * ldc + c] = v;
            }
        }
    }
}

// ---------------------------------------------------------------------------
// elementwise cast f32 -> bf16 (vectorized 4-wide)
// ---------------------------------------------------------------------------
__global__ void cast_bf16_kernel(const float4* __restrict__ in,
                                 ushort4* __restrict__ out, long long n4)
{
    long long i = (long long)blockIdx.x * blockDim.x + threadIdx.x;
    long long stride = (long long)gridDim.x * blockDim.x;
    for (; i < n4; i += stride) {
        float4 v = in[i];
        ushort4 o;
        o.x = f2bf(v.x); o.y = f2bf(v.y); o.z = f2bf(v.z); o.w = f2bf(v.w);
        out[i] = o;
    }
}

// ---------------------------------------------------------------------------
// transpose + cast: src f32 [R,C] -> dst bf16 [C, Rpad], rows R..Rpad-1 = 0.
// ---------------------------------------------------------------------------
__global__ void transpose_cast_kernel(const float* __restrict__ src,
                                      unsigned short* __restrict__ dst,
                                      int R, int C, int Rpad,
                                      long long sSrc, long long sDst)
{
    __shared__ float t[32][33];
    src += (long long)blockIdx.z * sSrc;
    dst += (long long)blockIdx.z * sDst;
    int r0 = blockIdx.x * 32, c0 = blockIdx.y * 32;
    int tx = threadIdx.x & 31, ty = threadIdx.x >> 5;
    #pragma unroll
    for (int i = 0; i < 32; i += 8) {
        int r = r0 + ty + i, c = c0 + tx;
        t[ty + i][tx] = (r < R && c < C) ? src[(long long)r * C + c] : 0.f;
    }
    __syncthreads();
    #pragma unroll
    for (int i = 0; i < 32; i += 8) {
        int c = c0 + ty + i, r = r0 + tx;
        if (c < C && r < Rpad)
            dst[(long long)c * Rpad + r] = f2bf(t[tx][ty + i]);
    }
}

// ---------------------------------------------------------------------------
// Ktot two-stage deterministic reduction over s.
// stage 1: partial[(b*NCH+ch)*D + d] = sum_{s in chunk} k[b,s,d]
//   grid: (B*NCH, D/256), block 256 (coalesced over d)
// ---------------------------------------------------------------------------
#define KTOT_NCH 16
__global__ void ktot_partial_kernel(const float* __restrict__ k,
                                    float* __restrict__ part,
                                    int B, int S, int D)
{
    int bch = blockIdx.x;
    int b  = bch / KTOT_NCH;
    int ch = bch % KTOT_NCH;
    int d  = blockIdx.y * 256 + threadIdx.x;
    if (d >= D) return;
    int len = (S + KTOT_NCH - 1) / KTOT_NCH;
    int lo = ch * len;
    int hi = lo + len < S ? lo + len : S;
    const float* kp = k + ((long long)b * S + lo) * D + d;
    float s = 0.f;
    for (int t = lo; t < hi; ++t, kp += D) s += *kp;
    part[(long long)bch * D + d] = s;
}

__global__ void ktot_finish_kernel(const float* __restrict__ part,
                                   float* __restrict__ ktot, int B, int D)
{
    int idx = blockIdx.x * blockDim.x + threadIdx.x;
    if (idx >= B * D) return;
    int b = idx / D, d = idx % D;
    float s = 0.f;
    #pragma unroll
    for (int ch = 0; ch < KTOT_NCH; ++ch)
        s += part[((long long)b * KTOT_NCH + ch) * D + d];
    ktot[idx] = s;
}

// ---------------------------------------------------------------------------
// kk[b,s,d] = (Ktot[b,d] + (e-1)*window_sum) / Z_s  -> bf16 (4-wide over d)
// ---------------------------------------------------------------------------
__global__ void kk_kernel(const float* __restrict__ k, const float* __restrict__ ktot,
                          unsigned short* __restrict__ kk, int B, int S, int D)
{
    long long idx = (long long)blockIdx.x * blockDim.x + threadIdx.x;
    int D4 = D >> 2;
    long long n4 = (long long)B * S * D4;
    if (idx >= n4) return;
    int d4 = (int)(idx % D4);
    long long bs = idx / D4;
    int s = (int)(bs % S);
    int b = (int)(bs / S);
    int lo = s - 2 > 0 ? s - 2 : 0;
    int hi = s + 2 < S - 1 ? s + 2 : S - 1;
    int c = hi - lo + 1;
    const float E = 2.718281828459045f;
    float Zinv = 1.f / ((float)(S - c) + E * (float)c);

    const float4* kp = (const float4*)(k + ((long long)b * S + lo) * D) + d4;
    float4 w = {0.f, 0.f, 0.f, 0.f};
    for (int t = lo; t <= hi; ++t, kp += D4) {
        float4 kv = *kp;
        w.x += kv.x; w.y += kv.y; w.z += kv.z; w.w += kv.w;
    }
    float4 tot = *((const float4*)(ktot + b * D) + d4);
    ushort4 o;
    o.x = f2bf((tot.x + (E - 1.f) * w.x) * Zinv);
    o.y = f2bf((tot.y + (E - 1.f) * w.y) * Zinv);
    o.z = f2bf((tot.z + (E - 1.f) * w.z) * Zinv);
    o.w = f2bf((tot.w + (E - 1.f) * w.w) * Zinv);
    ((ushort4*)(kk + ((long long)b * S + s) * D))[d4] = o;
}

// ---------------------------------------------------------------------------
// row softmax: fp32 scores [rows][Spad] (valid cols < S) -> bf16 P, pads = 0
// ---------------------------------------------------------------------------
__global__ void softmax_rows_bf16(const float* __restrict__ sc,
                                  unsigned short* __restrict__ P, int S, int Spad)
{
    long long row = blockIdx.x;
    const float* p = sc + row * (long long)Spad;
    unsigned short* o = P + row * (long long)Spad;
    int tid = threadIdx.x;
    __shared__ float red[256];

    float m = -INFINITY;
    for (int t = tid; t < S; t += 256) m = fmaxf(m, p[t]);
    red[tid] = m; __syncthreads();
    for (int s = 128; s > 0; s >>= 1) {
        if (tid < s) red[tid] = fmaxf(red[tid], red[tid + s]);
        __syncthreads();
    }
    m = red[0];
    __syncthreads();

    float sum = 0.f;
    for (int t = tid; t < S; t += 256) sum += __expf(p[t] - m);
    red[tid] = sum; __syncthreads();
    for (int s = 128; s > 0; s >>= 1) {
        if (tid < s) red[tid] += red[tid + s];
        __syncthreads();
    }
    float inv = 1.f / red[0];
    for (int t = tid; t < Spad; t += 256)
        o[t] = (t < S) ? f2bf(__expf(p[t] - m) * inv) : (unsigned short)0;
}

// ---------------------------------------------------------------------------
// whole-norm stats over z = a + f (fp64 partials, fixed deterministic tree)
// ---------------------------------------------------------------------------
__global__ void stats_kernel(const float4* __restrict__ a, const float4* __restrict__ f,
                             double* __restrict__ part, long long n4)
{
    __shared__ double rs[256], rs2[256];
    int tid = threadIdx.x;
    long long i = (long long)blockIdx.x * blockDim.x + tid;
    long long stride = (long long)gridDim.x * blockDim.x;
    double s = 0.0, s2 = 0.0;
    for (; i < n4; i += stride) {
        float4 av = a[i], fv = f[i];
        float z0 = av.x + fv.x, z1 = av.y + fv.y, z2 = av.z + fv.z, z3 = av.w + fv.w;
        s  += (double)z0 + (double)z1 + (double)z2 + (double)z3;
        s2 += (double)z0 * z0 + (double)z1 * z1 + (double)z2 * z2 + (double)z3 * z3;
    }
    rs[tid] = s; rs2[tid] = s2; __syncthreads();
    for (int k = 128; k > 0; k >>= 1) {
        if (tid < k) { rs[tid] += rs[tid + k]; rs2[tid] += rs2[tid + k]; }
        __syncthreads();
    }
    if (tid == 0) { part[2 * blockIdx.x] = rs[0]; part[2 * blockIdx.x + 1] = rs2[0]; }
}

__global__ void finish_stats(const double* __restrict__ part, int npart,
                             float* __restrict__ stats, double n)
{
    __shared__ double rs[256], rs2[256];
    int tid = threadIdx.x;
    double s = 0.0, s2 = 0.0;
    for (int i = tid; i < npart; i += 256) { s += part[2 * i]; s2 += part[2 * i + 1]; }
    rs[tid] = s; rs2[tid] = s2; __syncthreads();
    for (int k = 128; k > 0; k >>= 1) {
        if (tid < k) { rs[tid] += rs[tid + k]; rs2[tid] += rs2[tid + k]; }
        __syncthreads();
    }
    if (tid == 0) {
        double mu  = rs[0] / n;
        double var = rs2[0] / n - mu * mu;
        stats[0] = (float)mu;
        stats[1] = (float)(1.0 / sqrt(var + 1e-6));
    }
}

// norm apply, recomputing z = a + f on the fly; OUT_BF16 selects output type
template<bool OUT_BF16>
__global__ void norm_apply_kernel(const float4* __restrict__ a, const float4* __restrict__ f,
                                  const float4* __restrict__ nw, const float4* __restrict__ nb,
                                  const float* __restrict__ stats, void* __restrict__ out,
                                  long long n4)
{
    float mu = stats[0], rstd = stats[1];
    long long i = (long long)blockIdx.x * blockDim.x + threadIdx.x;
    long long stride = (long long)gridDim.x * blockDim.x;
    for (; i < n4; i += stride) {
        float4 av = a[i], fv = f[i], wv = nw[i], bv = nb[i];
        float o0 = (av.x + fv.x - mu) * rstd * wv.x + bv.x;
        float o1 = (av.y + fv.y - mu) * rstd * wv.y + bv.y;
        float o2 = (av.z + fv.z - mu) * rstd * wv.z + bv.z;
        float o3 = (av.w + fv.w - mu) * rstd * wv.w + bv.w;
        if (OUT_BF16) {
            ushort4 o; o.x = f2bf(o0); o.y = f2bf(o1); o.z = f2bf(o2); o.w = f2bf(o3);
            ((ushort4*)out)[i] = o;
        } else {
            float4 o = {o0, o1, o2, o3};
            ((float4*)out)[i] = o;
        }
    }
}

// ---------------------------------------------------------------------------
// host-side orchestration
// ---------------------------------------------------------------------------
static void gemm(bool outBf16, bool relu,
                 const unsigned short* A, const unsigned short* BT, const float* bias,
                 void* C, int M, int N, int K, int lda, int ldb, int ldc,
                 int batch, long long sA, long long sB, long long sC,
                 float alpha, hipStream_t st)
{
    dim3 grid((N + 127) / 128, (M + 127) / 128, batch);
    if (outBf16) {
        if (relu) gemm_bf16<true , true ><<<grid, 256, 0, st>>>(A, BT, bias, C, M, N, K, lda, ldb, ldc, sA, sB, sC, alpha);
        else      gemm_bf16<true , false><<<grid, 256, 0, st>>>(A, BT, bias, C, M, N, K, lda, ldb, ldc, sA, sB, sC, alpha);
    } else {
        if (relu) gemm_bf16<false, true ><<<grid, 256, 0, st>>>(A, BT, bias, C, M, N, K, lda, ldb, ldc, sA, sB, sC, alpha);
        else      gemm_bf16<false, false><<<grid, 256, 0, st>>>(A, BT, bias, C, M, N, K, lda, ldb, ldc, sA, sB, sC, alpha);
    }
}

struct Bufs {
    unsigned short *xb, *qb, *kkb, *vT, *P, *y1b, *h, *WqT, *WkT, *WvT, *W1T, *W2T;
    float *f32buf, *scores, *ktot, *ktot_part, *stats;
    double *part;
};

static void run_branch(const float* x, const float* const* w,  // 12 params
                       float* out, int B, int S, int D, const Bufs& wsb, hipStream_t st)
{
    const float *Wq = w[0], *bq = w[1], *Wk = w[2], *bk = w[3], *Wv = w[4], *bv = w[5];
    const float *W1 = w[6], *b1 = w[7], *W2 = w[8], *b2 = w[9], *nw = w[10], *nb = w[11];

    const int Spad = (S + 31) & ~31;
    const long long M = (long long)B * S;
    const long long n = M * D;
    const long long n4 = n / 4;
    const float inv_sqrt_d = (float)(1.0 / sqrt((double)D));
    const int D4 = 4 * D;

    // casts: x -> xb ; weights -> transposed bf16
    cast_bf16_kernel<<<1024, 256, 0, st>>>((const float4*)x, (ushort4*)wsb.xb, n4);
    transpose_cast_kernel<<<dim3((D + 31) / 32, (D + 31) / 32, 1), 256, 0, st>>>(Wq, wsb.WqT, D, D, D, 0, 0);
    transpose_cast_kernel<<<dim3((D + 31) / 32, (D + 31) / 32, 1), 256, 0, st>>>(Wk, wsb.WkT, D, D, D, 0, 0);
    transpose_cast_kernel<<<dim3((D + 31) / 32, (D + 31) / 32, 1), 256, 0, st>>>(Wv, wsb.WvT, D, D, D, 0, 0);
    transpose_cast_kernel<<<dim3((D + 31) / 32, (D4 + 31) / 32, 1), 256, 0, st>>>(W1, wsb.W1T, D, D4, D, 0, 0);
    transpose_cast_kernel<<<dim3((D4 + 31) / 32, (D + 31) / 32, 1), 256, 0, st>>>(W2, wsb.W2T, D4, D, D4, 0, 0);

    // q (bf16), k (fp32 -> f32buf)
    gemm(true , false, wsb.xb, wsb.WqT, bq, wsb.qb,    (int)M, D, D, D, D, D, 1, 0, 0, 0, 1.f, st);
    gemm(false, false, wsb.xb, wsb.WkT, bk, wsb.f32buf,(int)M, D, D, D, D, D, 1, 0, 0, 0, 1.f, st);

    // kk = softmax(band mask) @ k  (analytic)  -> bf16
    ktot_partial_kernel<<<dim3(B * KTOT_NCH, (D + 255) / 256), 256, 0, st>>>(
        wsb.f32buf, wsb.ktot_part, B, S, D);
    ktot_finish_kernel<<<(B * D + 255) / 256, 256, 0, st>>>(wsb.ktot_part, wsb.ktot, B, D);
    kk_kernel<<<(int)((n4 + 255) / 256), 256, 0, st>>>(wsb.f32buf, wsb.ktot, wsb.kkb, B, S, D);

    // v (fp32, overwrite k in f32buf) -> vT bf16 [B][D][Spad]
    gemm(false, false, wsb.xb, wsb.WvT, bv, wsb.f32buf, (int)M, D, D, D, D, D, 1, 0, 0, 0, 1.f, st);
    transpose_cast_kernel<<<dim3((Spad + 31) / 32, (D + 31) / 32, B), 256, 0, st>>>(
        wsb.f32buf, wsb.vT, S, D, Spad, (long long)S * D, (long long)D * Spad);

    // scores = q @ kk^T / sqrt(D)   (batched, fp32, ldc = Spad)
    gemm(false, false, wsb.qb, wsb.kkb, nullptr, wsb.scores, S, S, D, D, D, Spad,
         B, (long long)S * D, (long long)S * D, (long long)S * Spad, inv_sqrt_d, st);
    softmax_rows_bf16<<<(int)M, 256, 0, st>>>(wsb.scores, wsb.P, S, Spad);

    // attn = P @ v  (A = P [S,Spad] bf16, BT = vT [D,Spad]) -> f32buf
    gemm(false, false, wsb.P, wsb.vT, nullptr, wsb.f32buf, S, D, Spad, Spad, Spad, D,
         B, (long long)S * Spad, (long long)D * Spad, (long long)S * D, 1.f, st);

    // norm1: y1 = whole_norm(attn + x) -> bf16
    stats_kernel<<<1024, 256, 0, st>>>((const float4*)wsb.f32buf, (const float4*)x, wsb.part, n4);
    finish_stats<<<1, 256, 0, st>>>(wsb.part, 1024, wsb.stats, (double)n);
    norm_apply_kernel<true><<<2048, 256, 0, st>>>((const float4*)wsb.f32buf, (const float4*)x,
        (const float4*)nw, (const float4*)nb, wsb.stats, wsb.y1b, n4);

    // FFN
    gemm(true , true , wsb.y1b, wsb.W1T, b1, wsb.h,      (int)M, D4, D, D, D, D4, 1, 0, 0, 0, 1.f, st);
    gemm(false, false, wsb.h,   wsb.W2T, b2, wsb.f32buf, (int)M, D, D4, D4, D4, D, 1, 0, 0, 0, 1.f, st);

    // norm2: out = whole_norm(ffn + x) -> fp32
    stats_kernel<<<1024, 256, 0, st>>>((const float4*)wsb.f32buf, (const float4*)x, wsb.part, n4);
    finish_stats<<<1, 256, 0, st>>>(wsb.part, 1024, wsb.stats, (double)n);
    norm_apply_kernel<false><<<2048, 256, 0, st>>>((const float4*)wsb.f32buf, (const float4*)x,
        (const float4*)nw, (const float4*)nb, wsb.stats, out, n4);
}

extern "C" void kernel_launch(void* const* d_in, const int* in_sizes, int n_in,
                              void* d_out, int out_size, void* d_ws, size_t ws_size,
                              hipStream_t stream)
{
    const float* text  = (const float*)d_in[0];
    const float* image = (const float*)d_in[1];
    const float* tw[12];
    const float* iw[12];
    for (int i = 0; i < 12; ++i) tw[i] = (const float*)d_in[2 + i];
    for (int i = 0; i < 12; ++i) iw[i] = (const float*)d_in[14 + i];

    float* out_text = (float*)d_out;                 // [8,512,1024]
    float* out_img  = out_text + 8LL * 512 * 1024;   // [8,196,768]

    // workspace layout sized by the text branch (B=8,S=512,D=1024,Spad=512)
    char* p = (char*)d_ws;
    auto alloc = [&](long long bytes) {
        char* r = p;
        p += (bytes + 255) & ~255LL;
        return r;
    };
    const long long MD  = 4096LL * 1024;    // B*S*D
    const long long BDS = 8LL * 1024 * 512; // B*D*Spad
    const long long SS  = 8LL * 512 * 512;  // B*S*Spad
    Bufs b;
    b.xb     = (unsigned short*)alloc(MD * 2);
    b.qb     = (unsigned short*)alloc(MD * 2);
    b.kkb    = (unsigned short*)alloc(MD * 2);
    b.vT     = (unsigned short*)alloc(BDS * 2);
    b.P      = (unsigned short*)alloc(SS * 2);
    b.y1b    = (unsigned short*)alloc(MD * 2);
    b.h      = (unsigned short*)alloc(MD * 4 * 2);
    b.WqT    = (unsigned short*)alloc(1024LL * 1024 * 2);
    b.WkT    = (unsigned short*)alloc(1024LL * 1024 * 2);
    b.WvT    = (unsigned short*)alloc(1024LL * 1024 * 2);
    b.W1T    = (unsigned short*)alloc(4096LL * 1024 * 2);
    b.W2T    = (unsigned short*)alloc(4096LL * 1024 * 2);
    b.f32buf = (float*)alloc(MD * 4);
    b.scores = (float*)alloc(SS * 4);
    b.ktot      = (float*)alloc(8192LL * 4);
    b.ktot_part = (float*)alloc(8192LL * KTOT_NCH * 4);
    b.part   = (double*)alloc(2048LL * 8);
    b.stats  = (float*)alloc(256);

    run_branch(text,  tw, out_text, 8, 512, 1024, b, stream);
    run_branch(image, iw, out_img,  8, 196, 768,  b, stream);
}

// Round 4
// 582.888 us; speedup vs baseline: 6.3995x; 1.3059x over previous
//
#include <hip/hip_runtime.h>
#include <math.h>

typedef float  f32x4  __attribute__((ext_vector_type(4)));
typedef short  bf16x8 __attribute__((ext_vector_type(8)));

__device__ __forceinline__ unsigned short f2bf(float f) {
    union { float f; unsigned u; } v; v.f = f;
    unsigned u = v.u;
    return (unsigned short)((u + 0x7FFFu + ((u >> 16) & 1u)) >> 16);
}

#define GLOAD_LDS16(g, l)                                                      \
    __builtin_amdgcn_global_load_lds(                                          \
        (const __attribute__((address_space(1))) void*)(g),                    \
        (__attribute__((address_space(3))) void*)(l), 16, 0, 0)

// ---------------------------------------------------------------------------
// bf16 MFMA GEMM, m97 structure generalized to BM x BN tiles (BK=32, 4 waves,
// 2x2 wave grid, global_load_lds staging).
// A: bf16 [M,K] lda; BT: bf16 [N,K] ldb; C: fp32 or bf16, ldc.
// Batched via blockIdx.z (element strides sA/sB/sC).
// K % 32 == 0. Staging may over-read past M/N rows (buffers have slack).
// ---------------------------------------------------------------------------
template<int BM, int BN, bool OUT_BF16, bool RELU>
__global__ __launch_bounds__(256)
void gemm_bf16(const unsigned short* __restrict__ A,
               const unsigned short* __restrict__ BT,
               const float* __restrict__ bias, void* __restrict__ Cv,
               int M, int N, int K, int lda, int ldb, int ldc,
               long long sA, long long sB, long long sC, float alpha)
{
    constexpr int BK = 32;
    constexpr int WM = BM / 2, WN = BN / 2;   // per-wave output
    constexpr int MR = WM / 16, NR = WN / 16; // fragment repeats
    __shared__ unsigned short Asm[BM * BK];
    __shared__ unsigned short Bsm[BN * BK];

    A  += (long long)blockIdx.z * sA;
    BT += (long long)blockIdx.z * sB;
    char* Cb = (char*)Cv + (long long)blockIdx.z * sC * (OUT_BF16 ? 2 : 4);

    const int tid  = threadIdx.x;
    const int lane = tid & 63;
    const int wave = tid >> 6;         // 0..3
    const int wr   = wave >> 1;        // 0..1
    const int wc   = wave & 1;         // 0..1
    const int row0 = blockIdx.y * BM;
    const int col0 = blockIdx.x * BN;

    const int srow = tid >> 2;         // 0..63
    const int skel = (tid & 3) * 8;

    f32x4 acc[MR][NR] = {};

    const int lrow = lane & 15;
    const int lk   = (lane >> 4) * 8;

    for (int k0 = 0; k0 < K; k0 += BK) {
        #pragma unroll
        for (int is = 0; is < BM / 64; ++is) {
            const unsigned short* g =
                A + (long long)(row0 + is * 64 + srow) * lda + (k0 + skel);
            GLOAD_LDS16(g, &Asm[(is * 64 + srow) * BK + skel]);
        }
        #pragma unroll
        for (int is = 0; is < BN / 64; ++is) {
            const unsigned short* g =
                BT + (long long)(col0 + is * 64 + srow) * ldb + (k0 + skel);
            GLOAD_LDS16(g, &Bsm[(is * 64 + srow) * BK + skel]);
        }
        __syncthreads();

        bf16x8 af[MR], bfr[NR];
        #pragma unroll
        for (int mf = 0; mf < MR; ++mf)
            af[mf] = *(const bf16x8*)&Asm[(wr * WM + mf * 16 + lrow) * BK + lk];
        #pragma unroll
        for (int nf = 0; nf < NR; ++nf)
            bfr[nf] = *(const bf16x8*)&Bsm[(wc * WN + nf * 16 + lrow) * BK + lk];
        #pragma unroll
        for (int mf = 0; mf < MR; ++mf)
            #pragma unroll
            for (int nf = 0; nf < NR; ++nf)
                acc[mf][nf] = __builtin_amdgcn_mfma_f32_16x16x32_bf16(
                    af[mf], bfr[nf], acc[mf][nf], 0, 0, 0);
        __syncthreads();
    }

    // C/D layout: col = lane&15, row = (lane>>4)*4 + j   [m89 verified]
    const int crow = (lane >> 4) * 4;
    const int ccol = lane & 15;
    #pragma unroll
    for (int mf = 0; mf < MR; ++mf) {
        int rbase = row0 + wr * WM + mf * 16 + crow;
        #pragma unroll
        for (int nf = 0; nf < NR; ++nf) {
            int c = col0 + wc * WN + nf * 16 + ccol;
            if (c >= N) continue;
            float bv = bias ? bias[c] : 0.f;
            #pragma unroll
            for (int j = 0; j < 4; ++j) {
                int r = rbase + j;
                if (r >= M) continue;
                float v = acc[mf][nf][j] * alpha + bv;
                if (RELU) v = fmaxf(v, 0.f);
                if (OUT_BF16)
                    ((unsigned short*)Cb)[(long long)r * ldc + c] = f2bf(v);
                else
                    ((float*)Cb)[(long long)r * ldc + c] = v;
            }
        }
    }
}

template<int BM, int BN>
static void gemm_t(bool outBf16, bool relu,
                   const unsigned short* A, const unsigned short* BT, const float* bias,
                   void* C, int M, int N, int K, int lda, int ldb, int ldc,
                   int batch, long long sA, long long sB, long long sC,
                   float alpha, hipStream_t st)
{
    dim3 grid((N + BN - 1) / BN, (M + BM - 1) / BM, batch);
    if (outBf16) {
        if (relu) gemm_bf16<BM, BN, true , true ><<<grid, 256, 0, st>>>(A, BT, bias, C, M, N, K, lda, ldb, ldc, sA, sB, sC, alpha);
        else      gemm_bf16<BM, BN, true , false><<<grid, 256, 0, st>>>(A, BT, bias, C, M, N, K, lda, ldb, ldc, sA, sB, sC, alpha);
    } else {
        if (relu) gemm_bf16<BM, BN, false, true ><<<grid, 256, 0, st>>>(A, BT, bias, C, M, N, K, lda, ldb, ldc, sA, sB, sC, alpha);
        else      gemm_bf16<BM, BN, false, false><<<grid, 256, 0, st>>>(A, BT, bias, C, M, N, K, lda, ldb, ldc, sA, sB, sC, alpha);
    }
}

// ---------------------------------------------------------------------------
// elementwise cast f32 -> bf16 (vectorized 4-wide)
// ---------------------------------------------------------------------------
__global__ void cast_bf16_kernel(const float4* __restrict__ in,
                                 ushort4* __restrict__ out, long long n4)
{
    long long i = (long long)blockIdx.x * blockDim.x + threadIdx.x;
    long long stride = (long long)gridDim.x * blockDim.x;
    for (; i < n4; i += stride) {
        float4 v = in[i];
        ushort4 o;
        o.x = f2bf(v.x); o.y = f2bf(v.y); o.z = f2bf(v.z); o.w = f2bf(v.w);
        out[i] = o;
    }
}

// ---------------------------------------------------------------------------
// transpose + cast: src f32 [R,C] -> dst bf16 [C, Rpad], rows R..Rpad-1 = 0.
// ---------------------------------------------------------------------------
__global__ void transpose_cast_kernel(const float* __restrict__ src,
                                      unsigned short* __restrict__ dst,
                                      int R, int C, int Rpad,
                                      long long sSrc, long long sDst)
{
    __shared__ float t[32][33];
    src += (long long)blockIdx.z * sSrc;
    dst += (long long)blockIdx.z * sDst;
    int r0 = blockIdx.x * 32, c0 = blockIdx.y * 32;
    int tx = threadIdx.x & 31, ty = threadIdx.x >> 5;
    #pragma unroll
    for (int i = 0; i < 32; i += 8) {
        int r = r0 + ty + i, c = c0 + tx;
        t[ty + i][tx] = (r < R && c < C) ? src[(long long)r * C + c] : 0.f;
    }
    __syncthreads();
    #pragma unroll
    for (int i = 0; i < 32; i += 8) {
        int c = c0 + ty + i, r = r0 + tx;
        if (c < C && r < Rpad)
            dst[(long long)c * Rpad + r] = f2bf(t[tx][ty + i]);
    }
}

// ---------------------------------------------------------------------------
// Ktot two-stage deterministic reduction over s.
// ---------------------------------------------------------------------------
#define KTOT_NCH 16
__global__ void ktot_partial_kernel(const float* __restrict__ k,
                                    float* __restrict__ part,
                                    int B, int S, int D)
{
    int bch = blockIdx.x;
    int b  = bch / KTOT_NCH;
    int ch = bch % KTOT_NCH;
    int d  = blockIdx.y * 256 + threadIdx.x;
    if (d >= D) return;
    int len = (S + KTOT_NCH - 1) / KTOT_NCH;
    int lo = ch * len;
    int hi = lo + len < S ? lo + len : S;
    const float* kp = k + ((long long)b * S + lo) * D + d;
    float s = 0.f;
    for (int t = lo; t < hi; ++t, kp += D) s += *kp;
    part[(long long)bch * D + d] = s;
}

__global__ void ktot_finish_kernel(const float* __restrict__ part,
                                   float* __restrict__ ktot, int B, int D)
{
    int idx = blockIdx.x * blockDim.x + threadIdx.x;
    if (idx >= B * D) return;
    int b = idx / D, d = idx % D;
    float s = 0.f;
    #pragma unroll
    for (int ch = 0; ch < KTOT_NCH; ++ch)
        s += part[((long long)b * KTOT_NCH + ch) * D + d];
    ktot[idx] = s;
}

// ---------------------------------------------------------------------------
// kk[b,s,d] = (Ktot[b,d] + (e-1)*window_sum) / Z_s  -> bf16 (4-wide over d)
// ---------------------------------------------------------------------------
__global__ void kk_kernel(const float* __restrict__ k, const float* __restrict__ ktot,
                          unsigned short* __restrict__ kk, int B, int S, int D)
{
    long long idx = (long long)blockIdx.x * blockDim.x + threadIdx.x;
    int D4 = D >> 2;
    long long n4 = (long long)B * S * D4;
    if (idx >= n4) return;
    int d4 = (int)(idx % D4);
    long long bs = idx / D4;
    int s = (int)(bs % S);
    int b = (int)(bs / S);
    int lo = s - 2 > 0 ? s - 2 : 0;
    int hi = s + 2 < S - 1 ? s + 2 : S - 1;
    int c = hi - lo + 1;
    const float E = 2.718281828459045f;
    float Zinv = 1.f / ((float)(S - c) + E * (float)c);

    const float4* kp = (const float4*)(k + ((long long)b * S + lo) * D) + d4;
    float4 w = {0.f, 0.f, 0.f, 0.f};
    for (int t = lo; t <= hi; ++t, kp += D4) {
        float4 kv = *kp;
        w.x += kv.x; w.y += kv.y; w.z += kv.z; w.w += kv.w;
    }
    float4 tot = *((const float4*)(ktot + b * D) + d4);
    ushort4 o;
    o.x = f2bf((tot.x + (E - 1.f) * w.x) * Zinv);
    o.y = f2bf((tot.y + (E - 1.f) * w.y) * Zinv);
    o.z = f2bf((tot.z + (E - 1.f) * w.z) * Zinv);
    o.w = f2bf((tot.w + (E - 1.f) * w.w) * Zinv);
    ((ushort4*)(kk + ((long long)b * S + s) * D))[d4] = o;
}

// ---------------------------------------------------------------------------
// row softmax: fp32 scores [rows][Spad] (valid cols < S) -> bf16 P, pads = 0
// ---------------------------------------------------------------------------
__global__ void softmax_rows_bf16(const float* __restrict__ sc,
                                  unsigned short* __restrict__ P, int S, int Spad)
{
    long long row = blockIdx.x;
    const float* p = sc + row * (long long)Spad;
    unsigned short* o = P + row * (long long)Spad;
    int tid = threadIdx.x;
    __shared__ float red[256];

    float m = -INFINITY;
    for (int t = tid; t < S; t += 256) m = fmaxf(m, p[t]);
    red[tid] = m; __syncthreads();
    for (int s = 128; s > 0; s >>= 1) {
        if (tid < s) red[tid] = fmaxf(red[tid], red[tid + s]);
        __syncthreads();
    }
    m = red[0];
    __syncthreads();

    float sum = 0.f;
    for (int t = tid; t < S; t += 256) sum += __expf(p[t] - m);
    red[tid] = sum; __syncthreads();
    for (int s = 128; s > 0; s >>= 1) {
        if (tid < s) red[tid] += red[tid + s];
        __syncthreads();
    }
    float inv = 1.f / red[0];
    for (int t = tid; t < Spad; t += 256)
        o[t] = (t < S) ? f2bf(__expf(p[t] - m) * inv) : (unsigned short)0;
}

// ---------------------------------------------------------------------------
// whole-norm stats over z = a + f (fp64 partials, fixed deterministic tree)
// ---------------------------------------------------------------------------
__global__ void stats_kernel(const float4* __restrict__ a, const float4* __restrict__ f,
                             double* __restrict__ part, long long n4)
{
    __shared__ double rs[256], rs2[256];
    int tid = threadIdx.x;
    long long i = (long long)blockIdx.x * blockDim.x + tid;
    long long stride = (long long)gridDim.x * blockDim.x;
    double s = 0.0, s2 = 0.0;
    for (; i < n4; i += stride) {
        float4 av = a[i], fv = f[i];
        float z0 = av.x + fv.x, z1 = av.y + fv.y, z2 = av.z + fv.z, z3 = av.w + fv.w;
        s  += (double)z0 + (double)z1 + (double)z2 + (double)z3;
        s2 += (double)z0 * z0 + (double)z1 * z1 + (double)z2 * z2 + (double)z3 * z3;
    }
    rs[tid] = s; rs2[tid] = s2; __syncthreads();
    for (int k = 128; k > 0; k >>= 1) {
        if (tid < k) { rs[tid] += rs[tid + k]; rs2[tid] += rs2[tid + k]; }
        __syncthreads();
    }
    if (tid == 0) { part[2 * blockIdx.x] = rs[0]; part[2 * blockIdx.x + 1] = rs2[0]; }
}

__global__ void finish_stats(const double* __restrict__ part, int npart,
                             float* __restrict__ stats, double n)
{
    __shared__ double rs[256], rs2[256];
    int tid = threadIdx.x;
    double s = 0.0, s2 = 0.0;
    for (int i = tid; i < npart; i += 256) { s += part[2 * i]; s2 += part[2 * i + 1]; }
    rs[tid] = s; rs2[tid] = s2; __syncthreads();
    for (int k = 128; k > 0; k >>= 1) {
        if (tid < k) { rs[tid] += rs[tid + k]; rs2[tid] += rs2[tid + k]; }
        __syncthreads();
    }
    if (tid == 0) {
        double mu  = rs[0] / n;
        double var = rs2[0] / n - mu * mu;
        stats[0] = (float)mu;
        stats[1] = (float)(1.0 / sqrt(var + 1e-6));
    }
}

// norm apply, recomputing z = a + f on the fly; OUT_BF16 selects output type
template<bool OUT_BF16>
__global__ void norm_apply_kernel(const float4* __restrict__ a, const float4* __restrict__ f,
                                  const float4* __restrict__ nw, const float4* __restrict__ nb,
                                  const float* __restrict__ stats, void* __restrict__ out,
                                  long long n4)
{
    float mu = stats[0], rstd = stats[1];
    long long i = (long long)blockIdx.x * blockDim.x + threadIdx.x;
    long long stride = (long long)gridDim.x * blockDim.x;
    for (; i < n4; i += stride) {
        float4 av = a[i], fv = f[i], wv = nw[i], bv = nb[i];
        float o0 = (av.x + fv.x - mu) * rstd * wv.x + bv.x;
        float o1 = (av.y + fv.y - mu) * rstd * wv.y + bv.y;
        float o2 = (av.z + fv.z - mu) * rstd * wv.z + bv.z;
        float o3 = (av.w + fv.w - mu) * rstd * wv.w + bv.w;
        if (OUT_BF16) {
            ushort4 o; o.x = f2bf(o0); o.y = f2bf(o1); o.z = f2bf(o2); o.w = f2bf(o3);
            ((ushort4*)out)[i] = o;
        } else {
            float4 o = {o0, o1, o2, o3};
            ((float4*)out)[i] = o;
        }
    }
}

// ---------------------------------------------------------------------------
// host-side orchestration
// ---------------------------------------------------------------------------
struct Bufs {
    unsigned short *xb, *qb, *kkb, *vT, *P, *y1b, *h, *WqT, *WkT, *WvT, *W1T, *W2T;
    float *f32buf, *scores, *ktot, *ktot_part, *stats;
    double *part;
};

static void run_branch(const float* x, const float* const* w, bool big,
                       float* out, int B, int S, int D, const Bufs& wsb, hipStream_t st)
{
    const float *Wq = w[0], *bq = w[1], *Wk = w[2], *bk = w[3], *Wv = w[4], *bv = w[5];
    const float *W1 = w[6], *b1 = w[7], *W2 = w[8], *b2 = w[9], *nw = w[10], *nb = w[11];

    const int Spad = (S + 31) & ~31;
    const long long M = (long long)B * S;
    const long long n = M * D;
    const long long n4 = n / 4;
    const float inv_sqrt_d = (float)(1.0 / sqrt((double)D));
    const int D4 = 4 * D;

    // casts: x -> xb ; weights -> transposed bf16
    cast_bf16_kernel<<<1024, 256, 0, st>>>((const float4*)x, (ushort4*)wsb.xb, n4);
    transpose_cast_kernel<<<dim3((D + 31) / 32, (D + 31) / 32, 1), 256, 0, st>>>(Wq, wsb.WqT, D, D, D, 0, 0);
    transpose_cast_kernel<<<dim3((D + 31) / 32, (D + 31) / 32, 1), 256, 0, st>>>(Wk, wsb.WkT, D, D, D, 0, 0);
    transpose_cast_kernel<<<dim3((D + 31) / 32, (D + 31) / 32, 1), 256, 0, st>>>(Wv, wsb.WvT, D, D, D, 0, 0);
    transpose_cast_kernel<<<dim3((D + 31) / 32, (D4 + 31) / 32, 1), 256, 0, st>>>(W1, wsb.W1T, D, D4, D, 0, 0);
    transpose_cast_kernel<<<dim3((D4 + 31) / 32, (D + 31) / 32, 1), 256, 0, st>>>(W2, wsb.W2T, D4, D, D4, 0, 0);

    // q (bf16), k (fp32 -> f32buf): tiles chosen for >=2 blocks/CU
    if (big) {
        gemm_t<128, 64>(true , false, wsb.xb, wsb.WqT, bq, wsb.qb,    (int)M, D, D, D, D, D, 1, 0, 0, 0, 1.f, st);
        gemm_t<128, 64>(false, false, wsb.xb, wsb.WkT, bk, wsb.f32buf,(int)M, D, D, D, D, D, 1, 0, 0, 0, 1.f, st);
    } else {
        gemm_t<64, 64>(true , false, wsb.xb, wsb.WqT, bq, wsb.qb,    (int)M, D, D, D, D, D, 1, 0, 0, 0, 1.f, st);
        gemm_t<64, 64>(false, false, wsb.xb, wsb.WkT, bk, wsb.f32buf,(int)M, D, D, D, D, D, 1, 0, 0, 0, 1.f, st);
    }

    // kk = softmax(band mask) @ k  (analytic)  -> bf16
    ktot_partial_kernel<<<dim3(B * KTOT_NCH, (D + 255) / 256), 256, 0, st>>>(
        wsb.f32buf, wsb.ktot_part, B, S, D);
    ktot_finish_kernel<<<(B * D + 255) / 256, 256, 0, st>>>(wsb.ktot_part, wsb.ktot, B, D);
    kk_kernel<<<(int)((n4 + 255) / 256), 256, 0, st>>>(wsb.f32buf, wsb.ktot, wsb.kkb, B, S, D);

    // v (fp32, overwrite k in f32buf) -> vT bf16 [B][D][Spad]
    if (big)
        gemm_t<128, 64>(false, false, wsb.xb, wsb.WvT, bv, wsb.f32buf, (int)M, D, D, D, D, D, 1, 0, 0, 0, 1.f, st);
    else
        gemm_t<64, 64>(false, false, wsb.xb, wsb.WvT, bv, wsb.f32buf, (int)M, D, D, D, D, D, 1, 0, 0, 0, 1.f, st);
    transpose_cast_kernel<<<dim3((Spad + 31) / 32, (D + 31) / 32, B), 256, 0, st>>>(
        wsb.f32buf, wsb.vT, S, D, Spad, (long long)S * D, (long long)D * Spad);

    // scores = q @ kk^T / sqrt(D)   (batched, fp32, ldc = Spad)
    gemm_t<64, 64>(false, false, wsb.qb, wsb.kkb, nullptr, wsb.scores, S, S, D, D, D, Spad,
                   B, (long long)S * D, (long long)S * D, (long long)S * Spad, inv_sqrt_d, st);
    softmax_rows_bf16<<<(int)M, 256, 0, st>>>(wsb.scores, wsb.P, S, Spad);

    // attn = P @ v  (A = P [S,Spad] bf16, BT = vT [D,Spad]) -> f32buf
    if (big)
        gemm_t<128, 64>(false, false, wsb.P, wsb.vT, nullptr, wsb.f32buf, S, D, Spad, Spad, Spad, D,
                        B, (long long)S * Spad, (long long)D * Spad, (long long)S * D, 1.f, st);
    else
        gemm_t<64, 64>(false, false, wsb.P, wsb.vT, nullptr, wsb.f32buf, S, D, Spad, Spad, Spad, D,
                       B, (long long)S * Spad, (long long)D * Spad, (long long)S * D, 1.f, st);

    // norm1: y1 = whole_norm(attn + x) -> bf16
    stats_kernel<<<1024, 256, 0, st>>>((const float4*)wsb.f32buf, (const float4*)x, wsb.part, n4);
    finish_stats<<<1, 256, 0, st>>>(wsb.part, 1024, wsb.stats, (double)n);
    norm_apply_kernel<true><<<2048, 256, 0, st>>>((const float4*)wsb.f32buf, (const float4*)x,
        (const float4*)nw, (const float4*)nb, wsb.stats, wsb.y1b, n4);

    // FFN
    if (big) {
        gemm_t<128, 128>(true , true , wsb.y1b, wsb.W1T, b1, wsb.h,      (int)M, D4, D, D, D, D4, 1, 0, 0, 0, 1.f, st);
        gemm_t<128, 64 >(false, false, wsb.h,   wsb.W2T, b2, wsb.f32buf, (int)M, D, D4, D4, D4, D, 1, 0, 0, 0, 1.f, st);
    } else {
        gemm_t<64, 128>(true , true , wsb.y1b, wsb.W1T, b1, wsb.h,      (int)M, D4, D, D, D, D4, 1, 0, 0, 0, 1.f, st);
        gemm_t<64, 64 >(false, false, wsb.h,   wsb.W2T, b2, wsb.f32buf, (int)M, D, D4, D4, D4, D, 1, 0, 0, 0, 1.f, st);
    }

    // norm2: out = whole_norm(ffn + x) -> fp32
    stats_kernel<<<1024, 256, 0, st>>>((const float4*)wsb.f32buf, (const float4*)x, wsb.part, n4);
    finish_stats<<<1, 256, 0, st>>>(wsb.part, 1024, wsb.stats, (double)n);
    norm_apply_kernel<false><<<2048, 256, 0, st>>>((const float4*)wsb.f32buf, (const float4*)x,
        (const float4*)nw, (const float4*)nb, wsb.stats, out, n4);
}

extern "C" void kernel_launch(void* const* d_in, const int* in_sizes, int n_in,
                              void* d_out, int out_size, void* d_ws, size_t ws_size,
                              hipStream_t stream)
{
    const float* text  = (const float*)d_in[0];
    const float* image = (const float*)d_in[1];
    const float* tw[12];
    const float* iw[12];
    for (int i = 0; i < 12; ++i) tw[i] = (const float*)d_in[2 + i];
    for (int i = 0; i < 12; ++i) iw[i] = (const float*)d_in[14 + i];

    float* out_text = (float*)d_out;                 // [8,512,1024]
    float* out_img  = out_text + 8LL * 512 * 1024;   // [8,196,768]

    // workspace layout sized by the text branch (B=8,S=512,D=1024,Spad=512)
    char* p = (char*)d_ws;
    auto alloc = [&](long long bytes) {
        char* r = p;
        p += (bytes + 255) & ~255LL;
        return r;
    };
    const long long MD  = 4096LL * 1024;    // B*S*D
    const long long BDS = 8LL * 1024 * 512; // B*D*Spad
    const long long SS  = 8LL * 512 * 512;  // B*S*Spad
    Bufs b;
    b.xb     = (unsigned short*)alloc(MD * 2);
    b.qb     = (unsigned short*)alloc(MD * 2);
    b.kkb    = (unsigned short*)alloc(MD * 2);
    b.vT     = (unsigned short*)alloc(BDS * 2);
    b.P      = (unsigned short*)alloc(SS * 2);
    b.y1b    = (unsigned short*)alloc(MD * 2);
    b.h      = (unsigned short*)alloc(MD * 4 * 2);
    b.WqT    = (unsigned short*)alloc(1024LL * 1024 * 2);
    b.WkT    = (unsigned short*)alloc(1024LL * 1024 * 2);
    b.WvT    = (unsigned short*)alloc(1024LL * 1024 * 2);
    b.W1T    = (unsigned short*)alloc(4096LL * 1024 * 2);
    b.W2T    = (unsigned short*)alloc(4096LL * 1024 * 2);
    b.f32buf = (float*)alloc(MD * 4);
    b.scores = (float*)alloc(SS * 4);
    b.ktot      = (float*)alloc(8192LL * 4);
    b.ktot_part = (float*)alloc(8192LL * KTOT_NCH * 4);
    b.part   = (double*)alloc(2048LL * 8);
    b.stats  = (float*)alloc(256);

    run_branch(text,  tw, true,  out_text, 8, 512, 1024, b, stream);
    run_branch(image, iw, false, out_img,  8, 196, 768,  b, stream);
}

// Round 5
// 522.358 us; speedup vs baseline: 7.1411x; 1.1159x over previous
//
#include <hip/hip_runtime.h>
#include <math.h>

typedef float  f32x4  __attribute__((ext_vector_type(4)));
typedef short  bf16x8 __attribute__((ext_vector_type(8)));

__device__ __forceinline__ unsigned short f2bf(float f) {
    union { float f; unsigned u; } v; v.f = f;
    unsigned u = v.u;
    return (unsigned short)((u + 0x7FFFu + ((u >> 16) & 1u)) >> 16);
}
__device__ __forceinline__ float bf2f(unsigned short u) {
    union { unsigned u; float f; } v; v.u = (unsigned)u << 16; return v.f;
}

#define GLOAD_LDS16(g, l)                                                      \
    __builtin_amdgcn_global_load_lds(                                          \
        (const __attribute__((address_space(1))) void*)(g),                    \
        (__attribute__((address_space(3))) void*)(l), 16, 0, 0)

// ---------------------------------------------------------------------------
// bf16 MFMA GEMM, m97 structure, BM x BN tiles (BK=32, 4 waves 2x2,
// global_load_lds staging), bijective XCD swizzle (m204), m-fastest per XCD.
// A: bf16 [M,K] lda; BT: bf16 [N,K] ldb; C: fp32 or bf16, ldc.
// Batched via blockIdx.z (element strides sA/sB/sC). grid.x = gx*gy flat.
// ---------------------------------------------------------------------------
template<int BM, int BN, bool OUT_BF16, bool RELU>
__global__ __launch_bounds__(256)
void gemm_bf16(const unsigned short* __restrict__ A,
               const unsigned short* __restrict__ BT,
               const float* __restrict__ bias, void* __restrict__ Cv,
               int M, int N, int K, int lda, int ldb, int ldc,
               long long sA, long long sB, long long sC, float alpha,
               int gx, int gy)
{
    constexpr int BK = 32;
    constexpr int WM = BM / 2, WN = BN / 2;
    constexpr int MR = WM / 16, NR = WN / 16;
    __shared__ unsigned short Asm[BM * BK];
    __shared__ unsigned short Bsm[BN * BK];

    A  += (long long)blockIdx.z * sA;
    BT += (long long)blockIdx.z * sB;
    char* Cb = (char*)Cv + (long long)blockIdx.z * sC * (OUT_BF16 ? 2 : 4);

    // bijective XCD swizzle: each XCD gets a contiguous chunk, m fastest
    const int nwg = gx * gy;
    {
        int orig = blockIdx.x;
        int xcd = orig & 7, sidx = orig >> 3;
        int qq = nwg >> 3, rr = nwg & 7;
        int wg = (xcd < rr ? xcd * (qq + 1) : rr * (qq + 1) + (xcd - rr) * qq) + sidx;
        (void)wg;
        // row0/col0 from wg
        const int by = wg % gy;
        const int bx = wg / gy;
        __shared__ int rc[2];
        if (threadIdx.x == 0) { rc[0] = by * BM; rc[1] = bx * BN; }
        __syncthreads();
    }
    // recompute without shared (cheap, avoids extra barrier coupling)
    int orig = blockIdx.x;
    int xcd = orig & 7, sidx = orig >> 3;
    int qq = nwg >> 3, rr = nwg & 7;
    int wg = (xcd < rr ? xcd * (qq + 1) : rr * (qq + 1) + (xcd - rr) * qq) + sidx;
    const int row0 = (wg % gy) * BM;
    const int col0 = (wg / gy) * BN;

    const int tid  = threadIdx.x;
    const int lane = tid & 63;
    const int wave = tid >> 6;
    const int wr   = wave >> 1;
    const int wc   = wave & 1;

    const int srow = tid >> 2;
    const int skel = (tid & 3) * 8;

    f32x4 acc[MR][NR] = {};

    const int lrow = lane & 15;
    const int lk   = (lane >> 4) * 8;

    for (int k0 = 0; k0 < K; k0 += BK) {
        #pragma unroll
        for (int is = 0; is < BM / 64; ++is) {
            const unsigned short* g =
                A + (long long)(row0 + is * 64 + srow) * lda + (k0 + skel);
            GLOAD_LDS16(g, &Asm[(is * 64 + srow) * BK + skel]);
        }
        #pragma unroll
        for (int is = 0; is < BN / 64; ++is) {
            const unsigned short* g =
                BT + (long long)(col0 + is * 64 + srow) * ldb + (k0 + skel);
            GLOAD_LDS16(g, &Bsm[(is * 64 + srow) * BK + skel]);
        }
        __syncthreads();

        bf16x8 af[MR], bfr[NR];
        #pragma unroll
        for (int mf = 0; mf < MR; ++mf)
            af[mf] = *(const bf16x8*)&Asm[(wr * WM + mf * 16 + lrow) * BK + lk];
        #pragma unroll
        for (int nf = 0; nf < NR; ++nf)
            bfr[nf] = *(const bf16x8*)&Bsm[(wc * WN + nf * 16 + lrow) * BK + lk];
        #pragma unroll
        for (int mf = 0; mf < MR; ++mf)
            #pragma unroll
            for (int nf = 0; nf < NR; ++nf)
                acc[mf][nf] = __builtin_amdgcn_mfma_f32_16x16x32_bf16(
                    af[mf], bfr[nf], acc[mf][nf], 0, 0, 0);
        __syncthreads();
    }

    const int crow = (lane >> 4) * 4;
    const int ccol = lane & 15;
    #pragma unroll
    for (int mf = 0; mf < MR; ++mf) {
        int rbase = row0 + wr * WM + mf * 16 + crow;
        #pragma unroll
        for (int nf = 0; nf < NR; ++nf) {
            int c = col0 + wc * WN + nf * 16 + ccol;
            if (c >= N) continue;
            float bv = bias ? bias[c] : 0.f;
            #pragma unroll
            for (int j = 0; j < 4; ++j) {
                int r = rbase + j;
                if (r >= M) continue;
                float v = acc[mf][nf][j] * alpha + bv;
                if (RELU) v = fmaxf(v, 0.f);
                if (OUT_BF16)
                    ((unsigned short*)Cb)[(long long)r * ldc + c] = f2bf(v);
                else
                    ((float*)Cb)[(long long)r * ldc + c] = v;
            }
        }
    }
}

template<int BM, int BN>
static void gemm_t(bool outBf16, bool relu,
                   const unsigned short* A, const unsigned short* BT, const float* bias,
                   void* C, int M, int N, int K, int lda, int ldb, int ldc,
                   int batch, long long sA, long long sB, long long sC,
                   float alpha, hipStream_t st)
{
    int gx = (N + BN - 1) / BN, gy = (M + BM - 1) / BM;
    dim3 grid(gx * gy, 1, batch);
    if (outBf16) {
        if (relu) gemm_bf16<BM, BN, true , true ><<<grid, 256, 0, st>>>(A, BT, bias, C, M, N, K, lda, ldb, ldc, sA, sB, sC, alpha, gx, gy);
        else      gemm_bf16<BM, BN, true , false><<<grid, 256, 0, st>>>(A, BT, bias, C, M, N, K, lda, ldb, ldc, sA, sB, sC, alpha, gx, gy);
    } else {
        if (relu) gemm_bf16<BM, BN, false, true ><<<grid, 256, 0, st>>>(A, BT, bias, C, M, N, K, lda, ldb, ldc, sA, sB, sC, alpha, gx, gy);
        else      gemm_bf16<BM, BN, false, false><<<grid, 256, 0, st>>>(A, BT, bias, C, M, N, K, lda, ldb, ldc, sA, sB, sC, alpha, gx, gy);
    }
}

// ---------------------------------------------------------------------------
// split-K reduce: out = sum_s part[s] + bias (fixed order, deterministic)
// ---------------------------------------------------------------------------
__global__ void splitk_reduce_kernel(const float4* __restrict__ part,
                                     const float4* __restrict__ bias,
                                     float4* __restrict__ out,
                                     long long n4, int N4, int nsplit, long long stride4)
{
    long long i = (long long)blockIdx.x * blockDim.x + threadIdx.x;
    long long gs = (long long)gridDim.x * blockDim.x;
    for (; i < n4; i += gs) {
        float4 a = part[i];
        for (int s = 1; s < nsplit; ++s) {
            float4 b = part[(long long)s * stride4 + i];
            a.x += b.x; a.y += b.y; a.z += b.z; a.w += b.w;
        }
        float4 bv = bias[(int)(i % N4)];
        a.x += bv.x; a.y += bv.y; a.z += bv.z; a.w += bv.w;
        out[i] = a;
    }
}

// ---------------------------------------------------------------------------
// elementwise cast f32 -> bf16
// ---------------------------------------------------------------------------
__global__ void cast_bf16_kernel(const float4* __restrict__ in,
                                 ushort4* __restrict__ out, long long n4)
{
    long long i = (long long)blockIdx.x * blockDim.x + threadIdx.x;
    long long stride = (long long)gridDim.x * blockDim.x;
    for (; i < n4; i += stride) {
        float4 v = in[i];
        ushort4 o;
        o.x = f2bf(v.x); o.y = f2bf(v.y); o.z = f2bf(v.z); o.w = f2bf(v.w);
        out[i] = o;
    }
}

// ---------------------------------------------------------------------------
// transpose + cast: src f32 [R,C] -> dst bf16 [C, Rpad]
// ---------------------------------------------------------------------------
__global__ void transpose_cast_kernel(const float* __restrict__ src,
                                      unsigned short* __restrict__ dst,
                                      int R, int C, int Rpad,
                                      long long sSrc, long long sDst)
{
    __shared__ float t[32][33];
    src += (long long)blockIdx.z * sSrc;
    dst += (long long)blockIdx.z * sDst;
    int r0 = blockIdx.x * 32, c0 = blockIdx.y * 32;
    int tx = threadIdx.x & 31, ty = threadIdx.x >> 5;
    #pragma unroll
    for (int i = 0; i < 32; i += 8) {
        int r = r0 + ty + i, c = c0 + tx;
        t[ty + i][tx] = (r < R && c < C) ? src[(long long)r * C + c] : 0.f;
    }
    __syncthreads();
    #pragma unroll
    for (int i = 0; i < 32; i += 8) {
        int c = c0 + ty + i, r = r0 + tx;
        if (c < C && r < Rpad)
            dst[(long long)c * Rpad + r] = f2bf(t[tx][ty + i]);
    }
}

// transpose bf16 [R,C] (row stride ldS) -> bf16 [C, Rpad]
__global__ void transpose_bf16_kernel(const unsigned short* __restrict__ src,
                                      unsigned short* __restrict__ dst,
                                      int R, int C, int Rpad, int ldS,
                                      long long sSrc, long long sDst)
{
    __shared__ unsigned short t[32][33];
    src += (long long)blockIdx.z * sSrc;
    dst += (long long)blockIdx.z * sDst;
    int r0 = blockIdx.x * 32, c0 = blockIdx.y * 32;
    int tx = threadIdx.x & 31, ty = threadIdx.x >> 5;
    #pragma unroll
    for (int i = 0; i < 32; i += 8) {
        int r = r0 + ty + i, c = c0 + tx;
        t[ty + i][tx] = (r < R && c < C) ? src[(long long)r * ldS + c] : (unsigned short)0;
    }
    __syncthreads();
    #pragma unroll
    for (int i = 0; i < 32; i += 8) {
        int c = c0 + ty + i, r = r0 + tx;
        if (c < C && r < Rpad)
            dst[(long long)c * Rpad + r] = t[tx][ty + i];
    }
}

// ---------------------------------------------------------------------------
// Ktot two-stage deterministic reduction over s (bf16 input, strided ld)
// ---------------------------------------------------------------------------
#define KTOT_NCH 16
__global__ void ktot_partial_bf16(const unsigned short* __restrict__ k,
                                  float* __restrict__ part,
                                  int B, int S, int D, int ld)
{
    int bch = blockIdx.x;
    int b  = bch / KTOT_NCH;
    int ch = bch % KTOT_NCH;
    int d  = blockIdx.y * 256 + threadIdx.x;
    if (d >= D) return;
    int len = (S + KTOT_NCH - 1) / KTOT_NCH;
    int lo = ch * len;
    int hi = lo + len < S ? lo + len : S;
    const unsigned short* kp = k + ((long long)b * S + lo) * ld + d;
    float s = 0.f;
    for (int t = lo; t < hi; ++t, kp += ld) s += bf2f(*kp);
    part[(long long)bch * D + d] = s;
}

__global__ void ktot_finish_kernel(const float* __restrict__ part,
                                   float* __restrict__ ktot, int B, int D)
{
    int idx = blockIdx.x * blockDim.x + threadIdx.x;
    if (idx >= B * D) return;
    int b = idx / D, d = idx % D;
    float s = 0.f;
    #pragma unroll
    for (int ch = 0; ch < KTOT_NCH; ++ch)
        s += part[((long long)b * KTOT_NCH + ch) * D + d];
    ktot[idx] = s;
}

// ---------------------------------------------------------------------------
// kk[b,s,d] = (Ktot[b,d] + (e-1)*window_sum) / Z_s  from bf16 k (stride ld)
// ---------------------------------------------------------------------------
__global__ void kk_bf16_kernel(const unsigned short* __restrict__ k,
                               const float* __restrict__ ktot,
                               unsigned short* __restrict__ kk,
                               int B, int S, int D, int ld)
{
    long long idx = (long long)blockIdx.x * blockDim.x + threadIdx.x;
    int D4 = D >> 2;
    long long n4 = (long long)B * S * D4;
    if (idx >= n4) return;
    int d4 = (int)(idx % D4);
    long long bs = idx / D4;
    int s = (int)(bs % S);
    int b = (int)(bs / S);
    int lo = s - 2 > 0 ? s - 2 : 0;
    int hi = s + 2 < S - 1 ? s + 2 : S - 1;
    int c = hi - lo + 1;
    const float E = 2.718281828459045f;
    float Zinv = 1.f / ((float)(S - c) + E * (float)c);

    float w0 = 0.f, w1 = 0.f, w2 = 0.f, w3 = 0.f;
    const unsigned short* kp = k + ((long long)b * S + lo) * ld + d4 * 4;
    for (int t = lo; t <= hi; ++t, kp += ld) {
        ushort4 kv = *(const ushort4*)kp;
        w0 += bf2f(kv.x); w1 += bf2f(kv.y); w2 += bf2f(kv.z); w3 += bf2f(kv.w);
    }
    float4 tot = *((const float4*)(ktot + b * D) + d4);
    ushort4 o;
    o.x = f2bf((tot.x + (E - 1.f) * w0) * Zinv);
    o.y = f2bf((tot.y + (E - 1.f) * w1) * Zinv);
    o.z = f2bf((tot.z + (E - 1.f) * w2) * Zinv);
    o.w = f2bf((tot.w + (E - 1.f) * w3) * Zinv);
    ((ushort4*)(kk + ((long long)b * S + s) * D))[d4] = o;
}

// ---------------------------------------------------------------------------
// row softmax: fp32 scores [rows][Spad] -> bf16 P, pads = 0
// ---------------------------------------------------------------------------
__global__ void softmax_rows_bf16(const float* __restrict__ sc,
                                  unsigned short* __restrict__ P, int S, int Spad)
{
    long long row = blockIdx.x;
    const float* p = sc + row * (long long)Spad;
    unsigned short* o = P + row * (long long)Spad;
    int tid = threadIdx.x;
    __shared__ float red[256];

    float m = -INFINITY;
    for (int t = tid; t < S; t += 256) m = fmaxf(m, p[t]);
    red[tid] = m; __syncthreads();
    for (int s = 128; s > 0; s >>= 1) {
        if (tid < s) red[tid] = fmaxf(red[tid], red[tid + s]);
        __syncthreads();
    }
    m = red[0];
    __syncthreads();

    float sum = 0.f;
    for (int t = tid; t < S; t += 256) sum += __expf(p[t] - m);
    red[tid] = sum; __syncthreads();
    for (int s = 128; s > 0; s >>= 1) {
        if (tid < s) red[tid] += red[tid + s];
        __syncthreads();
    }
    float inv = 1.f / red[0];
    for (int t = tid; t < Spad; t += 256)
        o[t] = (t < S) ? f2bf(__expf(p[t] - m) * inv) : (unsigned short)0;
}

// ---------------------------------------------------------------------------
// whole-norm stats over z = a + f (fp64 partials, fixed deterministic tree)
// ---------------------------------------------------------------------------
__global__ void stats_kernel(const float4* __restrict__ a, const float4* __restrict__ f,
                             double* __restrict__ part, long long n4)
{
    __shared__ double rs[256], rs2[256];
    int tid = threadIdx.x;
    long long i = (long long)blockIdx.x * blockDim.x + tid;
    long long stride = (long long)gridDim.x * blockDim.x;
    double s = 0.0, s2 = 0.0;
    for (; i < n4; i += stride) {
        float4 av = a[i], fv = f[i];
        float z0 = av.x + fv.x, z1 = av.y + fv.y, z2 = av.z + fv.z, z3 = av.w + fv.w;
        s  += (double)z0 + (double)z1 + (double)z2 + (double)z3;
        s2 += (double)z0 * z0 + (double)z1 * z1 + (double)z2 * z2 + (double)z3 * z3;
    }
    rs[tid] = s; rs2[tid] = s2; __syncthreads();
    for (int k = 128; k > 0; k >>= 1) {
        if (tid < k) { rs[tid] += rs[tid + k]; rs2[tid] += rs2[tid + k]; }
        __syncthreads();
    }
    if (tid == 0) { part[2 * blockIdx.x] = rs[0]; part[2 * blockIdx.x + 1] = rs2[0]; }
}

__global__ void finish_stats(const double* __restrict__ part, int npart,
                             float* __restrict__ stats, double n)
{
    __shared__ double rs[256], rs2[256];
    int tid = threadIdx.x;
    double s = 0.0, s2 = 0.0;
    for (int i = tid; i < npart; i += 256) { s += part[2 * i]; s2 += part[2 * i + 1]; }
    rs[tid] = s; rs2[tid] = s2; __syncthreads();
    for (int k = 128; k > 0; k >>= 1) {
        if (tid < k) { rs[tid] += rs[tid + k]; rs2[tid] += rs2[tid + k]; }
        __syncthreads();
    }
    if (tid == 0) {
        double mu  = rs[0] / n;
        double var = rs2[0] / n - mu * mu;
        stats[0] = (float)mu;
        stats[1] = (float)(1.0 / sqrt(var + 1e-6));
    }
}

template<bool OUT_BF16>
__global__ void norm_apply_kernel(const float4* __restrict__ a, const float4* __restrict__ f,
                                  const float4* __restrict__ nw, const float4* __restrict__ nb,
                                  const float* __restrict__ stats, void* __restrict__ out,
                                  long long n4)
{
    float mu = stats[0], rstd = stats[1];
    long long i = (long long)blockIdx.x * blockDim.x + threadIdx.x;
    long long stride = (long long)gridDim.x * blockDim.x;
    for (; i < n4; i += stride) {
        float4 av = a[i], fv = f[i], wv = nw[i], bv = nb[i];
        float o0 = (av.x + fv.x - mu) * rstd * wv.x + bv.x;
        float o1 = (av.y + fv.y - mu) * rstd * wv.y + bv.y;
        float o2 = (av.z + fv.z - mu) * rstd * wv.z + bv.z;
        float o3 = (av.w + fv.w - mu) * rstd * wv.w + bv.w;
        if (OUT_BF16) {
            ushort4 o; o.x = f2bf(o0); o.y = f2bf(o1); o.z = f2bf(o2); o.w = f2bf(o3);
            ((ushort4*)out)[i] = o;
        } else {
            float4 o = {o0, o1, o2, o3};
            ((float4*)out)[i] = o;
        }
    }
}

// ---------------------------------------------------------------------------
// host-side orchestration
// ---------------------------------------------------------------------------
struct Bufs {
    unsigned short *xb, *qkv, *kkb, *vT, *P, *h, *WqkvT, *W1T, *W2T;
    float *f32buf, *bqkv, *ktot, *ktot_part, *stats;
    double *part;
};

static void run_branch(const float* x, const float* const* w, bool big,
                       float* out, int B, int S, int D, const Bufs& wsb, hipStream_t st)
{
    const float *Wq = w[0], *bq = w[1], *Wk = w[2], *bk = w[3], *Wv = w[4], *bv = w[5];
    const float *W1 = w[6], *b1 = w[7], *W2 = w[8], *b2 = w[9], *nw = w[10], *nb = w[11];

    const int Spad = (S + 31) & ~31;
    const long long M = (long long)B * S;
    const long long n = M * D;
    const long long n4 = n / 4;
    const float inv_sqrt_d = (float)(1.0 / sqrt((double)D));
    const int D3 = 3 * D, D4 = 4 * D;

    unsigned short* y1b = wsb.kkb;           // alias: kkb dead after scores GEMM
    float* scores = (float*)wsb.h;           // alias: h free until FFN1
    float* splitbuf = (float*)wsb.qkv;       // alias: qkv(+kkb) dead during FFN2

    // casts: x -> xb ; weights -> transposed bf16 (QKV concat), bias concat
    cast_bf16_kernel<<<1024, 256, 0, st>>>((const float4*)x, (ushort4*)wsb.xb, n4);
    transpose_cast_kernel<<<dim3((D + 31) / 32, (D + 31) / 32, 1), 256, 0, st>>>(Wq, wsb.WqkvT,            D, D, D, 0, 0);
    transpose_cast_kernel<<<dim3((D + 31) / 32, (D + 31) / 32, 1), 256, 0, st>>>(Wk, wsb.WqkvT + (long long)D * D,     D, D, D, 0, 0);
    transpose_cast_kernel<<<dim3((D + 31) / 32, (D + 31) / 32, 1), 256, 0, st>>>(Wv, wsb.WqkvT + 2LL * D * D, D, D, D, 0, 0);
    transpose_cast_kernel<<<dim3((D + 31) / 32, (D4 + 31) / 32, 1), 256, 0, st>>>(W1, wsb.W1T, D, D4, D, 0, 0);
    transpose_cast_kernel<<<dim3((D4 + 31) / 32, (D + 31) / 32, 1), 256, 0, st>>>(W2, wsb.W2T, D4, D, D4, 0, 0);
    hipMemcpyAsync(wsb.bqkv,         bq, D * sizeof(float), hipMemcpyDeviceToDevice, st);
    hipMemcpyAsync(wsb.bqkv + D,     bk, D * sizeof(float), hipMemcpyDeviceToDevice, st);
    hipMemcpyAsync(wsb.bqkv + 2 * D, bv, D * sizeof(float), hipMemcpyDeviceToDevice, st);

    // fused QKV: [M,3D] bf16
    if (big)
        gemm_t<128, 128>(true, false, wsb.xb, wsb.WqkvT, wsb.bqkv, wsb.qkv,
                         (int)M, D3, D, D, D, D3, 1, 0, 0, 0, 1.f, st);
    else
        gemm_t<128, 64>(true, false, wsb.xb, wsb.WqkvT, wsb.bqkv, wsb.qkv,
                        (int)M, D3, D, D, D, D3, 1, 0, 0, 0, 1.f, st);

    // kk = softmax(band mask) @ k  (analytic, bf16 k at column offset D)
    const unsigned short* kcol = wsb.qkv + D;
    ktot_partial_bf16<<<dim3(B * KTOT_NCH, (D + 255) / 256), 256, 0, st>>>(kcol, wsb.ktot_part, B, S, D, D3);
    ktot_finish_kernel<<<(B * D + 255) / 256, 256, 0, st>>>(wsb.ktot_part, wsb.ktot, B, D);
    kk_bf16_kernel<<<(int)((n4 + 255) / 256), 256, 0, st>>>(kcol, wsb.ktot, wsb.kkb, B, S, D, D3);

    // vT bf16 [B][D][Spad]  (v at column offset 2D)
    transpose_bf16_kernel<<<dim3((Spad + 31) / 32, (D + 31) / 32, B), 256, 0, st>>>(
        wsb.qkv + 2 * D, wsb.vT, S, D, Spad, D3, (long long)S * D3, (long long)D * Spad);

    // scores = q @ kk^T / sqrt(D)  (A = qkv cols 0..D, lda=3D; fp32 -> scores)
    gemm_t<64, 64>(false, false, wsb.qkv, wsb.kkb, nullptr, scores, S, S, D, D3, D, Spad,
                   B, (long long)S * D3, (long long)S * D, (long long)S * Spad, inv_sqrt_d, st);
    softmax_rows_bf16<<<(int)M, 256, 0, st>>>(scores, wsb.P, S, Spad);

    // attn = P @ v -> f32buf
    gemm_t<128, 64>(false, false, wsb.P, wsb.vT, nullptr, wsb.f32buf, S, D, Spad, Spad, Spad, D,
                    B, (long long)S * Spad, (long long)D * Spad, (long long)S * D, 1.f, st);

    // norm1: y1 = whole_norm(attn + x) -> bf16 (into kkb region)
    stats_kernel<<<1024, 256, 0, st>>>((const float4*)wsb.f32buf, (const float4*)x, wsb.part, n4);
    finish_stats<<<1, 256, 0, st>>>(wsb.part, 1024, wsb.stats, (double)n);
    norm_apply_kernel<true><<<2048, 256, 0, st>>>((const float4*)wsb.f32buf, (const float4*)x,
        (const float4*)nw, (const float4*)nb, wsb.stats, y1b, n4);

    // FFN1 -> h (bf16, relu)
    if (big)
        gemm_t<128, 128>(true, true, y1b, wsb.W1T, b1, wsb.h, (int)M, D4, D, D, D, D4, 1, 0, 0, 0, 1.f, st);
    else
        gemm_t<128, 64>(true, true, y1b, wsb.W1T, b1, wsb.h, (int)M, D4, D, D, D, D4, 1, 0, 0, 0, 1.f, st);

    // FFN2 split-K -> partials (fp32), then deterministic reduce + bias -> f32buf
    {
        int nsplit = big ? 2 : 4;
        int Ksp = D4 / nsplit;
        gemm_t<128, 64>(false, false, wsb.h, wsb.W2T, nullptr, splitbuf,
                        (int)M, D, Ksp, D4, D4, D,
                        nsplit, Ksp, Ksp, M * D, 1.f, st);
        splitk_reduce_kernel<<<2048, 256, 0, st>>>((const float4*)splitbuf, (const float4*)b2,
                                                   (float4*)wsb.f32buf, n4, D / 4, nsplit, n4);
    }

    // norm2: out = whole_norm(ffn + x) -> fp32
    stats_kernel<<<1024, 256, 0, st>>>((const float4*)wsb.f32buf, (const float4*)x, wsb.part, n4);
    finish_stats<<<1, 256, 0, st>>>(wsb.part, 1024, wsb.stats, (double)n);
    norm_apply_kernel<false><<<2048, 256, 0, st>>>((const float4*)wsb.f32buf, (const float4*)x,
        (const float4*)nw, (const float4*)nb, wsb.stats, out, n4);
}

extern "C" void kernel_launch(void* const* d_in, const int* in_sizes, int n_in,
                              void* d_out, int out_size, void* d_ws, size_t ws_size,
                              hipStream_t stream)
{
    const float* text  = (const float*)d_in[0];
    const float* image = (const float*)d_in[1];
    const float* tw[12];
    const float* iw[12];
    for (int i = 0; i < 12; ++i) tw[i] = (const float*)d_in[2 + i];
    for (int i = 0; i < 12; ++i) iw[i] = (const float*)d_in[14 + i];

    float* out_text = (float*)d_out;                 // [8,512,1024]
    float* out_img  = out_text + 8LL * 512 * 1024;   // [8,196,768]

    // workspace layout (text-branch sizes; image reuses)
    char* p = (char*)d_ws;
    auto alloc = [&](long long bytes) {
        char* r = p;
        p += (bytes + 255) & ~255LL;
        return r;
    };
    const long long MD  = 4096LL * 1024;    // B*S*D
    const long long BDS = 8LL * 1024 * 512; // B*D*Spad
    const long long SS  = 8LL * 512 * 512;  // B*S*Spad
    Bufs b;
    b.xb      = (unsigned short*)alloc(MD * 2);          // 8 MB
    b.qkv     = (unsigned short*)alloc(MD * 3 * 2);      // 24 MB (also splitbuf lo)
    b.kkb     = (unsigned short*)alloc(MD * 2);          // 8 MB (also y1b, splitbuf hi)
    b.vT      = (unsigned short*)alloc(BDS * 2);         // 8 MB
    b.P       = (unsigned short*)alloc(SS * 2);          // 4 MB
    b.h       = (unsigned short*)alloc(MD * 4 * 2);      // 32 MB (also scores)
    b.WqkvT   = (unsigned short*)alloc(3LL * 1024 * 1024 * 2);  // 6 MB
    b.W1T     = (unsigned short*)alloc(4096LL * 1024 * 2);      // 8 MB
    b.W2T     = (unsigned short*)alloc(4096LL * 1024 * 2);      // 8 MB
    b.f32buf  = (float*)alloc(MD * 4);                   // 16 MB
    b.bqkv    = (float*)alloc(3LL * 1024 * 4);
    b.ktot    = (float*)alloc(8192LL * 4);
    b.ktot_part = (float*)alloc(8192LL * KTOT_NCH * 4);
    b.part    = (double*)alloc(2048LL * 8);
    b.stats   = (float*)alloc(256);

    run_branch(text,  tw, true,  out_text, 8, 512, 1024, b, stream);
    run_branch(image, iw, false, out_img,  8, 196, 768,  b, stream);
}

// Round 6
// 503.263 us; speedup vs baseline: 7.4120x; 1.0379x over previous
//
#include <hip/hip_runtime.h>
#include <math.h>

typedef float  f32x4  __attribute__((ext_vector_type(4)));
typedef short  bf16x8 __attribute__((ext_vector_type(8)));

__device__ __forceinline__ unsigned short f2bf(float f) {
    union { float f; unsigned u; } v; v.f = f;
    unsigned u = v.u;
    return (unsigned short)((u + 0x7FFFu + ((u >> 16) & 1u)) >> 16);
}
__device__ __forceinline__ float bf2f(unsigned short u) {
    union { unsigned u; float f; } v; v.u = (unsigned)u << 16; return v.f;
}

#define GLOAD_LDS16(g, l)                                                      \
    __builtin_amdgcn_global_load_lds(                                          \
        (const __attribute__((address_space(1))) void*)(g),                    \
        (__attribute__((address_space(3))) void*)(l), 16, 0, 0)

// ---------------------------------------------------------------------------
// gemm2: 2-phase double-buffered bf16 MFMA GEMM (T3-minimum pipeline).
// 8 waves (2x4), BK=32, BM=2*MR*16, BN=4*NR*16. Stage of tile t+1 is issued
// BEFORE the ds_read+MFMA of tile t; ONE barrier per K-tile (its implicit
// vmcnt(0) drain is hidden under the compute).
// A: bf16 [M,K] lda; BT: bf16 [N,K] ldb; C: fp32 or bf16, ldc.
// Batched via blockIdx.z. K%32==0. A-staging may over-read rows past M
// (buffers have slack); C-writes are guarded.
// ---------------------------------------------------------------------------
template<int MR, int NR, bool OUT_BF16, bool RELU>
__global__ __launch_bounds__(512, 2)
void gemm2_bf16(const unsigned short* __restrict__ A,
                const unsigned short* __restrict__ BT,
                const float* __restrict__ bias, void* __restrict__ Cv,
                int M, int N, int K, int lda, int ldb, int ldc,
                long long sA, long long sB, long long sC, float alpha,
                int gx, int gy)
{
    constexpr int BK = 32;
    constexpr int WM = MR * 16, WN = NR * 16;
    constexpr int BM = 2 * WM, BN = 4 * WN;
    __shared__ unsigned short Asm[2][BM * BK];
    __shared__ unsigned short Bsm[2][BN * BK];

    A  += (long long)blockIdx.z * sA;
    BT += (long long)blockIdx.z * sB;
    char* Cb = (char*)Cv + (long long)blockIdx.z * sC * (OUT_BF16 ? 2 : 4);

    // bijective XCD swizzle (m204), m fastest within each XCD chunk
    const int nwg = gx * gy;
    int orig = blockIdx.x;
    int xcd = orig & 7, sidx = orig >> 3;
    int qq = nwg >> 3, rr = nwg & 7;
    int wg = (xcd < rr ? xcd * (qq + 1) : rr * (qq + 1) + (xcd - rr) * qq) + sidx;
    const int row0 = (wg % gy) * BM;
    const int col0 = (wg / gy) * BN;

    const int tid  = threadIdx.x;      // 0..511
    const int lane = tid & 63;
    const int wave = tid >> 6;         // 0..7
    const int wr   = wave >> 2;        // 0..1
    const int wc   = wave & 3;         // 0..3

    const int srow = tid >> 2;         // 0..127
    const int skel = (tid & 3) * 8;

    const int lrow = lane & 15;
    const int lk   = (lane >> 4) * 8;

    f32x4 acc[MR][NR] = {};

    auto stage = [&](int buf, int k0) {
        #pragma unroll
        for (int is = 0; is < BM / 128; ++is)
            GLOAD_LDS16(A + (long long)(row0 + is * 128 + srow) * lda + (k0 + skel),
                        &Asm[buf][(is * 128 + srow) * BK + skel]);
        #pragma unroll
        for (int is = 0; is < BN / 128; ++is)
            GLOAD_LDS16(BT + (long long)(col0 + is * 128 + srow) * ldb + (k0 + skel),
                        &Bsm[buf][(is * 128 + srow) * BK + skel]);
    };

    const int nt = K / BK;
    stage(0, 0);
    __syncthreads();
    int cur = 0;
    for (int t = 0; t < nt; ++t) {
        if (t + 1 < nt) stage(cur ^ 1, (t + 1) * BK);   // prefetch next tile

        bf16x8 af[MR], bfr[NR];
        #pragma unroll
        for (int mf = 0; mf < MR; ++mf)
            af[mf] = *(const bf16x8*)&Asm[cur][(wr * WM + mf * 16 + lrow) * BK + lk];
        #pragma unroll
        for (int nf = 0; nf < NR; ++nf)
            bfr[nf] = *(const bf16x8*)&Bsm[cur][(wc * WN + nf * 16 + lrow) * BK + lk];
        #pragma unroll
        for (int mf = 0; mf < MR; ++mf)
            #pragma unroll
            for (int nf = 0; nf < NR; ++nf)
                acc[mf][nf] = __builtin_amdgcn_mfma_f32_16x16x32_bf16(
                    af[mf], bfr[nf], acc[mf][nf], 0, 0, 0);

        __syncthreads();   // single barrier/tile: drains the prefetch too
        cur ^= 1;
    }

    // C/D layout: col = lane&15, row = (lane>>4)*4 + j   [m89 verified]
    const int crow = (lane >> 4) * 4;
    const int ccol = lane & 15;
    #pragma unroll
    for (int mf = 0; mf < MR; ++mf) {
        int rbase = row0 + wr * WM + mf * 16 + crow;
        #pragma unroll
        for (int nf = 0; nf < NR; ++nf) {
            int c = col0 + wc * WN + nf * 16 + ccol;
            if (c >= N) continue;
            float bv = bias ? bias[c] : 0.f;
            #pragma unroll
            for (int j = 0; j < 4; ++j) {
                int r = rbase + j;
                if (r >= M) continue;
                float v = acc[mf][nf][j] * alpha + bv;
                if (RELU) v = fmaxf(v, 0.f);
                if (OUT_BF16)
                    ((unsigned short*)Cb)[(long long)r * ldc + c] = f2bf(v);
                else
                    ((float*)Cb)[(long long)r * ldc + c] = v;
            }
        }
    }
}

template<int MR, int NR>
static void gemm2_t(bool outBf16, bool relu,
                    const unsigned short* A, const unsigned short* BT, const float* bias,
                    void* C, int M, int N, int K, int lda, int ldb, int ldc,
                    int batch, long long sA, long long sB, long long sC,
                    float alpha, hipStream_t st)
{
    const int BM = 2 * MR * 16, BN = 4 * NR * 16;
    int gx = (N + BN - 1) / BN, gy = (M + BM - 1) / BM;
    dim3 grid(gx * gy, 1, batch);
    if (outBf16) {
        if (relu) gemm2_bf16<MR, NR, true , true ><<<grid, 512, 0, st>>>(A, BT, bias, C, M, N, K, lda, ldb, ldc, sA, sB, sC, alpha, gx, gy);
        else      gemm2_bf16<MR, NR, true , false><<<grid, 512, 0, st>>>(A, BT, bias, C, M, N, K, lda, ldb, ldc, sA, sB, sC, alpha, gx, gy);
    } else {
        if (relu) gemm2_bf16<MR, NR, false, true ><<<grid, 512, 0, st>>>(A, BT, bias, C, M, N, K, lda, ldb, ldc, sA, sB, sC, alpha, gx, gy);
        else      gemm2_bf16<MR, NR, false, false><<<grid, 512, 0, st>>>(A, BT, bias, C, M, N, K, lda, ldb, ldc, sA, sB, sC, alpha, gx, gy);
    }
}

// ---------------------------------------------------------------------------
// old m97-structure engine, kept for the small batched GEMMs (scores, PV)
// ---------------------------------------------------------------------------
template<int BM, int BN, bool OUT_BF16>
__global__ __launch_bounds__(256)
void gemm_bf16(const unsigned short* __restrict__ A,
               const unsigned short* __restrict__ BT,
               const float* __restrict__ bias, void* __restrict__ Cv,
               int M, int N, int K, int lda, int ldb, int ldc,
               long long sA, long long sB, long long sC, float alpha,
               int gx, int gy)
{
    constexpr int BK = 32;
    constexpr int WM = BM / 2, WN = BN / 2;
    constexpr int MR = WM / 16, NR = WN / 16;
    __shared__ unsigned short Asm[BM * BK];
    __shared__ unsigned short Bsm[BN * BK];

    A  += (long long)blockIdx.z * sA;
    BT += (long long)blockIdx.z * sB;
    char* Cb = (char*)Cv + (long long)blockIdx.z * sC * (OUT_BF16 ? 2 : 4);

    const int nwg = gx * gy;
    int orig = blockIdx.x;
    int xcd = orig & 7, sidx = orig >> 3;
    int qq = nwg >> 3, rr = nwg & 7;
    int wg = (xcd < rr ? xcd * (qq + 1) : rr * (qq + 1) + (xcd - rr) * qq) + sidx;
    const int row0 = (wg % gy) * BM;
    const int col0 = (wg / gy) * BN;

    const int tid  = threadIdx.x;
    const int lane = tid & 63;
    const int wave = tid >> 6;
    const int wr   = wave >> 1;
    const int wc   = wave & 1;

    const int srow = tid >> 2;
    const int skel = (tid & 3) * 8;

    f32x4 acc[MR][NR] = {};

    const int lrow = lane & 15;
    const int lk   = (lane >> 4) * 8;

    for (int k0 = 0; k0 < K; k0 += BK) {
        #pragma unroll
        for (int is = 0; is < BM / 64; ++is)
            GLOAD_LDS16(A + (long long)(row0 + is * 64 + srow) * lda + (k0 + skel),
                        &Asm[(is * 64 + srow) * BK + skel]);
        #pragma unroll
        for (int is = 0; is < BN / 64; ++is)
            GLOAD_LDS16(BT + (long long)(col0 + is * 64 + srow) * ldb + (k0 + skel),
                        &Bsm[(is * 64 + srow) * BK + skel]);
        __syncthreads();

        bf16x8 af[MR], bfr[NR];
        #pragma unroll
        for (int mf = 0; mf < MR; ++mf)
            af[mf] = *(const bf16x8*)&Asm[(wr * WM + mf * 16 + lrow) * BK + lk];
        #pragma unroll
        for (int nf = 0; nf < NR; ++nf)
            bfr[nf] = *(const bf16x8*)&Bsm[(wc * WN + nf * 16 + lrow) * BK + lk];
        #pragma unroll
        for (int mf = 0; mf < MR; ++mf)
            #pragma unroll
            for (int nf = 0; nf < NR; ++nf)
                acc[mf][nf] = __builtin_amdgcn_mfma_f32_16x16x32_bf16(
                    af[mf], bfr[nf], acc[mf][nf], 0, 0, 0);
        __syncthreads();
    }

    const int crow = (lane >> 4) * 4;
    const int ccol = lane & 15;
    #pragma unroll
    for (int mf = 0; mf < MR; ++mf) {
        int rbase = row0 + wr * WM + mf * 16 + crow;
        #pragma unroll
        for (int nf = 0; nf < NR; ++nf) {
            int c = col0 + wc * WN + nf * 16 + ccol;
            if (c >= N) continue;
            float bv = bias ? bias[c] : 0.f;
            #pragma unroll
            for (int j = 0; j < 4; ++j) {
                int r = rbase + j;
                if (r >= M) continue;
                float v = acc[mf][nf][j] * alpha + bv;
                if (OUT_BF16)
                    ((unsigned short*)Cb)[(long long)r * ldc + c] = f2bf(v);
                else
                    ((float*)Cb)[(long long)r * ldc + c] = v;
            }
        }
    }
}

template<int BM, int BN>
static void gemm_t(bool outBf16,
                   const unsigned short* A, const unsigned short* BT, const float* bias,
                   void* C, int M, int N, int K, int lda, int ldb, int ldc,
                   int batch, long long sA, long long sB, long long sC,
                   float alpha, hipStream_t st)
{
    int gx = (N + BN - 1) / BN, gy = (M + BM - 1) / BM;
    dim3 grid(gx * gy, 1, batch);
    if (outBf16)
        gemm_bf16<BM, BN, true ><<<grid, 256, 0, st>>>(A, BT, bias, C, M, N, K, lda, ldb, ldc, sA, sB, sC, alpha, gx, gy);
    else
        gemm_bf16<BM, BN, false><<<grid, 256, 0, st>>>(A, BT, bias, C, M, N, K, lda, ldb, ldc, sA, sB, sC, alpha, gx, gy);
}

// ---------------------------------------------------------------------------
// split-K reduce + bias + residual(x) + whole-norm stats, fused (deterministic)
// ---------------------------------------------------------------------------
__global__ void splitk_stats_kernel(const float4* __restrict__ part,
                                    const float4* __restrict__ bias,
                                    const float4* __restrict__ x,
                                    float4* __restrict__ z,
                                    double* __restrict__ dpart,
                                    long long n4, int N4, int nsplit, long long stride4)
{
    __shared__ double rs[256], rs2[256];
    int tid = threadIdx.x;
    long long i = (long long)blockIdx.x * blockDim.x + tid;
    long long gs = (long long)gridDim.x * blockDim.x;
    double s = 0.0, s2 = 0.0;
    for (; i < n4; i += gs) {
        float4 a = part[i];
        for (int sp = 1; sp < nsplit; ++sp) {
            float4 b = part[(long long)sp * stride4 + i];
            a.x += b.x; a.y += b.y; a.z += b.z; a.w += b.w;
        }
        float4 bv = bias[(int)(i % N4)];
        float4 xv = x[i];
        a.x += bv.x + xv.x; a.y += bv.y + xv.y; a.z += bv.z + xv.z; a.w += bv.w + xv.w;
        z[i] = a;
        s  += (double)a.x + (double)a.y + (double)a.z + (double)a.w;
        s2 += (double)a.x * a.x + (double)a.y * a.y + (double)a.z * a.z + (double)a.w * a.w;
    }
    rs[tid] = s; rs2[tid] = s2; __syncthreads();
    for (int k = 128; k > 0; k >>= 1) {
        if (tid < k) { rs[tid] += rs[tid + k]; rs2[tid] += rs2[tid + k]; }
        __syncthreads();
    }
    if (tid == 0) { dpart[2 * blockIdx.x] = rs[0]; dpart[2 * blockIdx.x + 1] = rs2[0]; }
}

// norm apply reading z directly (z already includes residual), fp32 out
__global__ void norm_apply_z_kernel(const float4* __restrict__ z,
                                    const float4* __restrict__ nw, const float4* __restrict__ nb,
                                    const float* __restrict__ stats, float4* __restrict__ out,
                                    long long n4)
{
    float mu = stats[0], rstd = stats[1];
    long long i = (long long)blockIdx.x * blockDim.x + threadIdx.x;
    long long stride = (long long)gridDim.x * blockDim.x;
    for (; i < n4; i += stride) {
        float4 zv = z[i], wv = nw[i], bv = nb[i];
        float4 o;
        o.x = (zv.x - mu) * rstd * wv.x + bv.x;
        o.y = (zv.y - mu) * rstd * wv.y + bv.y;
        o.z = (zv.z - mu) * rstd * wv.z + bv.z;
        o.w = (zv.w - mu) * rstd * wv.w + bv.w;
        out[i] = o;
    }
}

// ---------------------------------------------------------------------------
// elementwise cast f32 -> bf16
// ---------------------------------------------------------------------------
__global__ void cast_bf16_kernel(const float4* __restrict__ in,
                                 ushort4* __restrict__ out, long long n4)
{
    long long i = (long long)blockIdx.x * blockDim.x + threadIdx.x;
    long long stride = (long long)gridDim.x * blockDim.x;
    for (; i < n4; i += stride) {
        float4 v = in[i];
        ushort4 o;
        o.x = f2bf(v.x); o.y = f2bf(v.y); o.z = f2bf(v.z); o.w = f2bf(v.w);
        out[i] = o;
    }
}

// ---------------------------------------------------------------------------
// transpose + cast: src f32 [R,C] -> dst bf16 [C, Rpad]
// ---------------------------------------------------------------------------
__global__ void transpose_cast_kernel(const float* __restrict__ src,
                                      unsigned short* __restrict__ dst,
                                      int R, int C, int Rpad,
                                      long long sSrc, long long sDst)
{
    __shared__ float t[32][33];
    src += (long long)blockIdx.z * sSrc;
    dst += (long long)blockIdx.z * sDst;
    int r0 = blockIdx.x * 32, c0 = blockIdx.y * 32;
    int tx = threadIdx.x & 31, ty = threadIdx.x >> 5;
    #pragma unroll
    for (int i = 0; i < 32; i += 8) {
        int r = r0 + ty + i, c = c0 + tx;
        t[ty + i][tx] = (r < R && c < C) ? src[(long long)r * C + c] : 0.f;
    }
    __syncthreads();
    #pragma unroll
    for (int i = 0; i < 32; i += 8) {
        int c = c0 + ty + i, r = r0 + tx;
        if (c < C && r < Rpad)
            dst[(long long)c * Rpad + r] = f2bf(t[tx][ty + i]);
    }
}

// transpose bf16 [R,C] (row stride ldS) -> bf16 [C, Rpad]
__global__ void transpose_bf16_kernel(const unsigned short* __restrict__ src,
                                      unsigned short* __restrict__ dst,
                                      int R, int C, int Rpad, int ldS,
                                      long long sSrc, long long sDst)
{
    __shared__ unsigned short t[32][33];
    src += (long long)blockIdx.z * sSrc;
    dst += (long long)blockIdx.z * sDst;
    int r0 = blockIdx.x * 32, c0 = blockIdx.y * 32;
    int tx = threadIdx.x & 31, ty = threadIdx.x >> 5;
    #pragma unroll
    for (int i = 0; i < 32; i += 8) {
        int r = r0 + ty + i, c = c0 + tx;
        t[ty + i][tx] = (r < R && c < C) ? src[(long long)r * ldS + c] : (unsigned short)0;
    }
    __syncthreads();
    #pragma unroll
    for (int i = 0; i < 32; i += 8) {
        int c = c0 + ty + i, r = r0 + tx;
        if (c < C && r < Rpad)
            dst[(long long)c * Rpad + r] = t[tx][ty + i];
    }
}

// ---------------------------------------------------------------------------
// Ktot two-stage deterministic reduction over s (bf16 input, strided ld)
// ---------------------------------------------------------------------------
#define KTOT_NCH 16
__global__ void ktot_partial_bf16(const unsigned short* __restrict__ k,
                                  float* __restrict__ part,
                                  int B, int S, int D, int ld)
{
    int bch = blockIdx.x;
    int b  = bch / KTOT_NCH;
    int ch = bch % KTOT_NCH;
    int d  = blockIdx.y * 256 + threadIdx.x;
    if (d >= D) return;
    int len = (S + KTOT_NCH - 1) / KTOT_NCH;
    int lo = ch * len;
    int hi = lo + len < S ? lo + len : S;
    const unsigned short* kp = k + ((long long)b * S + lo) * ld + d;
    float s = 0.f;
    for (int t = lo; t < hi; ++t, kp += ld) s += bf2f(*kp);
    part[(long long)bch * D + d] = s;
}

__global__ void ktot_finish_kernel(const float* __restrict__ part,
                                   float* __restrict__ ktot, int B, int D)
{
    int idx = blockIdx.x * blockDim.x + threadIdx.x;
    if (idx >= B * D) return;
    int b = idx / D, d = idx % D;
    float s = 0.f;
    #pragma unroll
    for (int ch = 0; ch < KTOT_NCH; ++ch)
        s += part[((long long)b * KTOT_NCH + ch) * D + d];
    ktot[idx] = s;
}

// ---------------------------------------------------------------------------
// kk[b,s,d] = (Ktot[b,d] + (e-1)*window_sum) / Z_s  from bf16 k (stride ld)
// ---------------------------------------------------------------------------
__global__ void kk_bf16_kernel(const unsigned short* __restrict__ k,
                               const float* __restrict__ ktot,
                               unsigned short* __restrict__ kk,
                               int B, int S, int D, int ld)
{
    long long idx = (long long)blockIdx.x * blockDim.x + threadIdx.x;
    int D4 = D >> 2;
    long long n4 = (long long)B * S * D4;
    if (idx >= n4) return;
    int d4 = (int)(idx % D4);
    long long bs = idx / D4;
    int s = (int)(bs % S);
    int b = (int)(bs / S);
    int lo = s - 2 > 0 ? s - 2 : 0;
    int hi = s + 2 < S - 1 ? s + 2 : S - 1;
    int c = hi - lo + 1;
    const float E = 2.718281828459045f;
    float Zinv = 1.f / ((float)(S - c) + E * (float)c);

    float w0 = 0.f, w1 = 0.f, w2 = 0.f, w3 = 0.f;
    const unsigned short* kp = k + ((long long)b * S + lo) * ld + d4 * 4;
    for (int t = lo; t <= hi; ++t, kp += ld) {
        ushort4 kv = *(const ushort4*)kp;
        w0 += bf2f(kv.x); w1 += bf2f(kv.y); w2 += bf2f(kv.z); w3 += bf2f(kv.w);
    }
    float4 tot = *((const float4*)(ktot + b * D) + d4);
    ushort4 o;
    o.x = f2bf((tot.x + (E - 1.f) * w0) * Zinv);
    o.y = f2bf((tot.y + (E - 1.f) * w1) * Zinv);
    o.z = f2bf((tot.z + (E - 1.f) * w2) * Zinv);
    o.w = f2bf((tot.w + (E - 1.f) * w3) * Zinv);
    ((ushort4*)(kk + ((long long)b * S + s) * D))[d4] = o;
}

// ---------------------------------------------------------------------------
// row softmax: fp32 scores [rows][Spad] -> bf16 P, pads = 0
// ---------------------------------------------------------------------------
__global__ void softmax_rows_bf16(const float* __restrict__ sc,
                                  unsigned short* __restrict__ P, int S, int Spad)
{
    long long row = blockIdx.x;
    const float* p = sc + row * (long long)Spad;
    unsigned short* o = P + row * (long long)Spad;
    int tid = threadIdx.x;
    __shared__ float red[256];

    float m = -INFINITY;
    for (int t = tid; t < S; t += 256) m = fmaxf(m, p[t]);
    red[tid] = m; __syncthreads();
    for (int s = 128; s > 0; s >>= 1) {
        if (tid < s) red[tid] = fmaxf(red[tid], red[tid + s]);
        __syncthreads();
    }
    m = red[0];
    __syncthreads();

    float sum = 0.f;
    for (int t = tid; t < S; t += 256) sum += __expf(p[t] - m);
    red[tid] = sum; __syncthreads();
    for (int s = 128; s > 0; s >>= 1) {
        if (tid < s) red[tid] += red[tid + s];
        __syncthreads();
    }
    float inv = 1.f / red[0];
    for (int t = tid; t < Spad; t += 256)
        o[t] = (t < S) ? f2bf(__expf(p[t] - m) * inv) : (unsigned short)0;
}

// ---------------------------------------------------------------------------
// whole-norm stats over z = a + f (fp64 partials, fixed deterministic tree)
// ---------------------------------------------------------------------------
__global__ void stats_kernel(const float4* __restrict__ a, const float4* __restrict__ f,
                             double* __restrict__ part, long long n4)
{
    __shared__ double rs[256], rs2[256];
    int tid = threadIdx.x;
    long long i = (long long)blockIdx.x * blockDim.x + tid;
    long long stride = (long long)gridDim.x * blockDim.x;
    double s = 0.0, s2 = 0.0;
    for (; i < n4; i += stride) {
        float4 av = a[i], fv = f[i];
        float z0 = av.x + fv.x, z1 = av.y + fv.y, z2 = av.z + fv.z, z3 = av.w + fv.w;
        s  += (double)z0 + (double)z1 + (double)z2 + (double)z3;
        s2 += (double)z0 * z0 + (double)z1 * z1 + (double)z2 * z2 + (double)z3 * z3;
    }
    rs[tid] = s; rs2[tid] = s2; __syncthreads();
    for (int k = 128; k > 0; k >>= 1) {
        if (tid < k) { rs[tid] += rs[tid + k]; rs2[tid] += rs2[tid + k]; }
        __syncthreads();
    }
    if (tid == 0) { part[2 * blockIdx.x] = rs[0]; part[2 * blockIdx.x + 1] = rs2[0]; }
}

__global__ void finish_stats(const double* __restrict__ part, int npart,
                             float* __restrict__ stats, double n)
{
    __shared__ double rs[256], rs2[256];
    int tid = threadIdx.x;
    double s = 0.0, s2 = 0.0;
    for (int i = tid; i < npart; i += 256) { s += part[2 * i]; s2 += part[2 * i + 1]; }
    rs[tid] = s; rs2[tid] = s2; __syncthreads();
    for (int k = 128; k > 0; k >>= 1) {
        if (tid < k) { rs[tid] += rs[tid + k]; rs2[tid] += rs2[tid + k]; }
        __syncthreads();
    }
    if (tid == 0) {
        double mu  = rs[0] / n;
        double var = rs2[0] / n - mu * mu;
        stats[0] = (float)mu;
        stats[1] = (float)(1.0 / sqrt(var + 1e-6));
    }
}

// norm apply recomputing z = a + f, bf16 out (used for norm1 -> y1)
__global__ void norm_apply_kernel(const float4* __restrict__ a, const float4* __restrict__ f,
                                  const float4* __restrict__ nw, const float4* __restrict__ nb,
                                  const float* __restrict__ stats, ushort4* __restrict__ out,
                                  long long n4)
{
    float mu = stats[0], rstd = stats[1];
    long long i = (long long)blockIdx.x * blockDim.x + threadIdx.x;
    long long stride = (long long)gridDim.x * blockDim.x;
    for (; i < n4; i += stride) {
        float4 av = a[i], fv = f[i], wv = nw[i], bv = nb[i];
        ushort4 o;
        o.x = f2bf((av.x + fv.x - mu) * rstd * wv.x + bv.x);
        o.y = f2bf((av.y + fv.y - mu) * rstd * wv.y + bv.y);
        o.z = f2bf((av.z + fv.z - mu) * rstd * wv.z + bv.z);
        o.w = f2bf((av.w + fv.w - mu) * rstd * wv.w + bv.w);
        out[i] = o;
    }
}

// ---------------------------------------------------------------------------
// host-side orchestration
// ---------------------------------------------------------------------------
struct Bufs {
    unsigned short *xb, *qkv, *kkb, *vT, *P, *h, *WqkvT, *W1T, *W2T;
    float *f32buf, *bqkv, *ktot, *ktot_part, *stats;
    double *part;
};

static void run_branch(const float* x, const float* const* w, bool big,
                       float* out, int B, int S, int D, const Bufs& wsb, hipStream_t st)
{
    const float *Wq = w[0], *bq = w[1], *Wk = w[2], *bk = w[3], *Wv = w[4], *bv = w[5];
    const float *W1 = w[6], *b1 = w[7], *W2 = w[8], *b2 = w[9], *nw = w[10], *nb = w[11];

    const int Spad = (S + 31) & ~31;
    const long long M = (long long)B * S;
    const long long n = M * D;
    const long long n4 = n / 4;
    const float inv_sqrt_d = (float)(1.0 / sqrt((double)D));
    const int D3 = 3 * D, D4 = 4 * D;

    unsigned short* y1b = wsb.kkb;           // alias: kkb dead after scores GEMM
    float* scores = (float*)wsb.h;           // alias: h free until FFN1
    float* splitbuf = (float*)wsb.qkv;       // alias: qkv(+kkb) dead during FFN2

    // casts: x -> xb ; weights -> transposed bf16 (QKV concat), bias concat
    cast_bf16_kernel<<<1024, 256, 0, st>>>((const float4*)x, (ushort4*)wsb.xb, n4);
    transpose_cast_kernel<<<dim3((D + 31) / 32, (D + 31) / 32, 1), 256, 0, st>>>(Wq, wsb.WqkvT,               D, D, D, 0, 0);
    transpose_cast_kernel<<<dim3((D + 31) / 32, (D + 31) / 32, 1), 256, 0, st>>>(Wk, wsb.WqkvT + (long long)D * D, D, D, D, 0, 0);
    transpose_cast_kernel<<<dim3((D + 31) / 32, (D + 31) / 32, 1), 256, 0, st>>>(Wv, wsb.WqkvT + 2LL * D * D, D, D, D, 0, 0);
    transpose_cast_kernel<<<dim3((D + 31) / 32, (D4 + 31) / 32, 1), 256, 0, st>>>(W1, wsb.W1T, D, D4, D, 0, 0);
    transpose_cast_kernel<<<dim3((D4 + 31) / 32, (D + 31) / 32, 1), 256, 0, st>>>(W2, wsb.W2T, D4, D, D4, 0, 0);
    hipMemcpyAsync(wsb.bqkv,         bq, D * sizeof(float), hipMemcpyDeviceToDevice, st);
    hipMemcpyAsync(wsb.bqkv + D,     bk, D * sizeof(float), hipMemcpyDeviceToDevice, st);
    hipMemcpyAsync(wsb.bqkv + 2 * D, bv, D * sizeof(float), hipMemcpyDeviceToDevice, st);

    // fused QKV: [M,3D] bf16 (2-phase engine)
    if (big)
        gemm2_t<8, 2>(true, false, wsb.xb, wsb.WqkvT, wsb.bqkv, wsb.qkv,
                      (int)M, D3, D, D, D, D3, 1, 0, 0, 0, 1.f, st);   // 256x128
    else
        gemm2_t<4, 2>(true, false, wsb.xb, wsb.WqkvT, wsb.bqkv, wsb.qkv,
                      (int)M, D3, D, D, D, D3, 1, 0, 0, 0, 1.f, st);   // 128x128

    // kk = softmax(band mask) @ k  (analytic, bf16 k at column offset D)
    const unsigned short* kcol = wsb.qkv + D;
    ktot_partial_bf16<<<dim3(B * KTOT_NCH, (D + 255) / 256), 256, 0, st>>>(kcol, wsb.ktot_part, B, S, D, D3);
    ktot_finish_kernel<<<(B * D + 255) / 256, 256, 0, st>>>(wsb.ktot_part, wsb.ktot, B, D);
    kk_bf16_kernel<<<(int)((n4 + 255) / 256), 256, 0, st>>>(kcol, wsb.ktot, wsb.kkb, B, S, D, D3);

    // vT bf16 [B][D][Spad]  (v at column offset 2D)
    transpose_bf16_kernel<<<dim3((Spad + 31) / 32, (D + 31) / 32, B), 256, 0, st>>>(
        wsb.qkv + 2 * D, wsb.vT, S, D, Spad, D3, (long long)S * D3, (long long)D * Spad);

    // scores = q @ kk^T / sqrt(D)
    gemm_t<64, 64>(false, wsb.qkv, wsb.kkb, nullptr, scores, S, S, D, D3, D, Spad,
                   B, (long long)S * D3, (long long)S * D, (long long)S * Spad, inv_sqrt_d, st);
    softmax_rows_bf16<<<(int)M, 256, 0, st>>>(scores, wsb.P, S, Spad);

    // attn = P @ v -> f32buf
    gemm_t<128, 64>(false, wsb.P, wsb.vT, nullptr, wsb.f32buf, S, D, Spad, Spad, Spad, D,
                    B, (long long)S * Spad, (long long)D * Spad, (long long)S * D, 1.f, st);

    // norm1: y1 = whole_norm(attn + x) -> bf16 (into kkb region)
    stats_kernel<<<1024, 256, 0, st>>>((const float4*)wsb.f32buf, (const float4*)x, wsb.part, n4);
    finish_stats<<<1, 256, 0, st>>>(wsb.part, 1024, wsb.stats, (double)n);
    norm_apply_kernel<<<2048, 256, 0, st>>>((const float4*)wsb.f32buf, (const float4*)x,
        (const float4*)nw, (const float4*)nb, wsb.stats, (ushort4*)y1b, n4);

    // FFN1 -> h (bf16, relu), 2-phase engine
    if (big)
        gemm2_t<8, 4>(true, true, y1b, wsb.W1T, b1, wsb.h, (int)M, D4, D, D, D, D4, 1, 0, 0, 0, 1.f, st);  // 256x256
    else
        gemm2_t<4, 2>(true, true, y1b, wsb.W1T, b1, wsb.h, (int)M, D4, D, D, D, D4, 1, 0, 0, 0, 1.f, st);  // 128x128

    // FFN2 split-K -> partials (fp32), fused reduce+bias+residual+stats
    {
        int nsplit = big ? 2 : 4;
        int Ksp = D4 / nsplit;
        if (big)
            gemm2_t<8, 2>(false, false, wsb.h, wsb.W2T, nullptr, splitbuf,
                          (int)M, D, Ksp, D4, D4, D,
                          nsplit, Ksp, Ksp, M * D, 1.f, st);           // 256x128
        else
            gemm2_t<4, 2>(false, false, wsb.h, wsb.W2T, nullptr, splitbuf,
                          (int)M, D, Ksp, D4, D4, D,
                          nsplit, Ksp, Ksp, M * D, 1.f, st);           // 128x128
        splitk_stats_kernel<<<1024, 256, 0, st>>>((const float4*)splitbuf, (const float4*)b2,
                                                  (const float4*)x, (float4*)wsb.f32buf,
                                                  wsb.part, n4, D / 4, nsplit, n4);
        finish_stats<<<1, 256, 0, st>>>(wsb.part, 1024, wsb.stats, (double)n);
        norm_apply_z_kernel<<<2048, 256, 0, st>>>((const float4*)wsb.f32buf,
            (const float4*)nw, (const float4*)nb, wsb.stats, (float4*)out, n4);
    }
}

extern "C" void kernel_launch(void* const* d_in, const int* in_sizes, int n_in,
                              void* d_out, int out_size, void* d_ws, size_t ws_size,
                              hipStream_t stream)
{
    const float* text  = (const float*)d_in[0];
    const float* image = (const float*)d_in[1];
    const float* tw[12];
    const float* iw[12];
    for (int i = 0; i < 12; ++i) tw[i] = (const float*)d_in[2 + i];
    for (int i = 0; i < 12; ++i) iw[i] = (const float*)d_in[14 + i];

    float* out_text = (float*)d_out;                 // [8,512,1024]
    float* out_img  = out_text + 8LL * 512 * 1024;   // [8,196,768]

    // workspace layout (text-branch sizes; image reuses)
    char* p = (char*)d_ws;
    auto alloc = [&](long long bytes) {
        char* r = p;
        p += (bytes + 255) & ~255LL;
        return r;
    };
    const long long MD  = 4096LL * 1024;    // B*S*D
    const long long BDS = 8LL * 1024 * 512; // B*D*Spad
    const long long SS  = 8LL * 512 * 512;  // B*S*Spad
    Bufs b;
    b.xb      = (unsigned short*)alloc(MD * 2);          // 8 MB
    b.qkv     = (unsigned short*)alloc(MD * 3 * 2);      // 24 MB (also splitbuf lo)
    b.kkb     = (unsigned short*)alloc(MD * 2);          // 8 MB (also y1b, splitbuf hi)
    b.vT      = (unsigned short*)alloc(BDS * 2);         // 8 MB
    b.P       = (unsigned short*)alloc(SS * 2);          // 4 MB
    b.h       = (unsigned short*)alloc(MD * 4 * 2);      // 32 MB (also scores)
    b.WqkvT   = (unsigned short*)alloc(3LL * 1024 * 1024 * 2);  // 6 MB
    b.W1T     = (unsigned short*)alloc(4096LL * 1024 * 2);      // 8 MB
    b.W2T     = (unsigned short*)alloc(4096LL * 1024 * 2);      // 8 MB
    b.f32buf  = (float*)alloc(MD * 4);                   // 16 MB
    b.bqkv    = (float*)alloc(3LL * 1024 * 4);
    b.ktot    = (float*)alloc(8192LL * 4);
    b.ktot_part = (float*)alloc(8192LL * KTOT_NCH * 4);
    b.part    = (double*)alloc(2048LL * 8);
    b.stats   = (float*)alloc(256);

    run_branch(text,  tw, true,  out_text, 8, 512, 1024, b, stream);
    run_branch(image, iw, false, out_img,  8, 196, 768,  b, stream);
}